// Round 2
// baseline (18951.472 us; speedup 1.0000x reference)
//
#include <hip/hip_runtime.h>
#include <math.h>

#define USERN 100000
#define ITEMN 200000
#define NND   300000
#define DD    64
#define HH    128
#define FF    16
#define EDG   3000000
#define LEAKY_A 0.5f
#define LN_EPS  1e-5f

__device__ __forceinline__ float leaky(float x){ return x>0.f ? x : LEAKY_A*x; }
__device__ __forceinline__ unsigned fenc(float f){ unsigned u=__float_as_uint(f); return (u&0x80000000u)? ~u : (u|0x80000000u); }
__device__ __forceinline__ float fdec(unsigned u){ return (u&0x80000000u)? __uint_as_float(u&0x7fffffffu) : __uint_as_float(~u); }

// ---------------- init: x = concat(uE, iE); out = x ----------------
__global__ __launch_bounds__(256) void k_init(const float* __restrict__ uE, const float* __restrict__ iE,
                        float* __restrict__ x, float* __restrict__ out){
  int tot=NND*DD;
  for(int idx=blockIdx.x*256+threadIdx.x; idx<tot; idx+=gridDim.x*256){
    int n=idx>>6;
    float v=(n<USERN)? uE[idx] : iE[idx-USERN*DD];
    x[idx]=v; out[idx]=v;
  }
}

// ---------------- hv = H @ attn for both u and i (hv[0:64]=u, hv[64:128]=i) ----------------
__global__ __launch_bounds__(128) void k_hv(const float* __restrict__ uH,const float* __restrict__ iH,
      const float* __restrict__ uA,const float* __restrict__ iA,float* __restrict__ hv){
  int t=threadIdx.x;
  const float* H=(t<64)? uH:iH;
  const float* A=(t<64)? uA:iA;
  int d=t&63;
  float s=0.f;
  for(int h=0;h<HH;h++) s=fmaf(H[d*HH+h],A[h],s);
  hv[t]=s;
}

// ---------------- a[n] = E[n,:] . hv ----------------
__global__ __launch_bounds__(256) void k_att(const float* __restrict__ E, const float* __restrict__ hvp,
      float* __restrict__ a, int U){
  __shared__ float hs[64];
  int tid=threadIdx.x;
  if(tid<64) hs[tid]=hvp[tid];
  __syncthreads();
  int wave=tid>>6, lane=tid&63;
  for(int g=blockIdx.x*4+wave; g<U/4; g+=gridDim.x*4){
    int n0=g*4;
    #pragma unroll
    for(int m=0;m<4;m++){
      float p=E[(size_t)(n0+m)*DD+lane]*hs[lane];
      #pragma unroll
      for(int off=32;off;off>>=1) p+=__shfl_xor(p,off,64);
      if(lane==0) a[n0+m]=p;
    }
  }
}

// ---------------- softmax reductions over node axis ----------------
__global__ __launch_bounds__(256) void k_redmax(const float* __restrict__ a, int n, unsigned* slot){
  float v=-3.0e38f;
  for(int i=blockIdx.x*256+threadIdx.x;i<n;i+=gridDim.x*256) v=fmaxf(v,a[i]);
  #pragma unroll
  for(int off=32;off;off>>=1) v=fmaxf(v,__shfl_xor(v,off,64));
  if((threadIdx.x&63)==0) atomicMax(slot, fenc(v));
}

__global__ __launch_bounds__(256) void k_sumexp(const float* __restrict__ a, int n,
      const unsigned* __restrict__ mslot, float* ssum){
  float mx=fdec(*mslot);
  float s=0.f;
  for(int i=blockIdx.x*256+threadIdx.x;i<n;i+=gridDim.x*256) s+=expf(a[i]-mx);
  #pragma unroll
  for(int off=32;off;off>>=1) s+=__shfl_xor(s,off,64);
  if((threadIdx.x&63)==0) atomicAdd(ssum, s);
}

// a[n] <- exp(a[n]-mx)/sum   (softmax scale per node)
__global__ __launch_bounds__(256) void k_scale_a(float* __restrict__ a,int n,
      const unsigned* __restrict__ mslot,const float* __restrict__ ssum){
  float mx=fdec(*mslot); float inv=1.f/(*ssum);
  for(int i=blockIdx.x*256+threadIdx.x;i<n;i+=gridDim.x*256) a[i]=expf(a[i]-mx)*inv;
}

// ---------------- SpMM: tem[r,:] += val * x[c,:] (atomic) ----------------
__global__ __launch_bounds__(256) void k_spmm(const float* __restrict__ vals, const int* __restrict__ rows,
      const int* __restrict__ cols, const float* __restrict__ x, float* __restrict__ tem){
  long long tot=(long long)EDG*DD;
  long long stride=(long long)gridDim.x*256;
  for(long long idx=(long long)blockIdx.x*256+threadIdx.x; idx<tot; idx+=stride){
    int e=(int)(idx>>6), d=(int)(idx&63);
    float v=vals[e];
    int r=rows[e], c=cols[e];
    atomicAdd(&tem[(size_t)r*DD+d], v*x[(size_t)c*DD+d]);
  }
}

// ---------------- G[d1,d2] += sum_n s[n]*E[n,d1]*x[n,d2] ----------------
__global__ __launch_bounds__(256) void k_gacc(const float* __restrict__ E,const float* __restrict__ sca,
      const float* __restrict__ x,float* __restrict__ G,int U){
  __shared__ __align__(16) float es[4][256];
  int tid=threadIdx.x, wave=tid>>6, lane=tid&63;
  float acc[64];
  #pragma unroll
  for(int j=0;j<64;j++) acc[j]=0.f;
  float* esw=es[wave];
  for(int g=blockIdx.x*4+wave; g<U/4; g+=gridDim.x*4){
    int n0=g*4;
    float xv[4];
    #pragma unroll
    for(int m=0;m<4;m++){
      float sc=sca[n0+m];
      esw[m*64+lane]=E[(size_t)(n0+m)*DD+lane]*sc;
      xv[m]=x[(size_t)(n0+m)*DD+lane];
    }
    #pragma unroll
    for(int d4=0;d4<16;d4++){
      float4 eb[4];
      #pragma unroll
      for(int m=0;m<4;m++) eb[m]=((const float4*)(esw+m*64))[d4];
      #pragma unroll
      for(int c=0;c<4;c++){
        #pragma unroll
        for(int m=0;m<4;m++) acc[d4*4+c]=fmaf(((const float*)&eb[m])[c],xv[m],acc[d4*4+c]);
      }
    }
  }
  #pragma unroll
  for(int j=0;j<64;j++) atomicAdd(&G[j*64+lane],acc[j]);
}

// ---------------- M = H @ (H^T @ G)  (blockIdx 0=user, 1=item) ----------------
__global__ __launch_bounds__(256) void k_tm(const float* __restrict__ uH,const float* __restrict__ iH,
      const float* __restrict__ G,float* __restrict__ Mo){
  __shared__ __align__(16) float Hs[64*HH];
  __shared__ __align__(16) float Gs[64*64];
  __shared__ __align__(16) float Ts[HH*64];
  const float* H = blockIdx.x ? iH : uH;
  const float* Gp = G + blockIdx.x*4096;
  float* Mp = Mo + blockIdx.x*4096;
  int tid=threadIdx.x;
  for(int k=tid;k<64*HH;k+=256) Hs[k]=H[k];
  for(int k=tid;k<4096;k+=256) Gs[k]=Gp[k];
  __syncthreads();
  int lane=tid&63, wq=tid>>6;
  float tac[32];
  #pragma unroll
  for(int k=0;k<32;k++) tac[k]=0.f;
  for(int d1=0;d1<64;d1++){
    float gv=Gs[d1*64+lane];
    const float4* hrow=(const float4*)(Hs+d1*HH+wq*32);
    #pragma unroll
    for(int k4=0;k4<8;k4++){
      float4 hb=hrow[k4];
      tac[k4*4+0]=fmaf(hb.x,gv,tac[k4*4+0]);
      tac[k4*4+1]=fmaf(hb.y,gv,tac[k4*4+1]);
      tac[k4*4+2]=fmaf(hb.z,gv,tac[k4*4+2]);
      tac[k4*4+3]=fmaf(hb.w,gv,tac[k4*4+3]);
    }
  }
  #pragma unroll
  for(int k=0;k<32;k++) Ts[(wq*32+k)*64+lane]=tac[k];
  __syncthreads();
  float mac[16];
  #pragma unroll
  for(int k=0;k<16;k++) mac[k]=0.f;
  for(int h=0;h<HH;h++){
    float tv=Ts[h*64+lane];
    #pragma unroll
    for(int k=0;k<16;k++) mac[k]=fmaf(Hs[(wq*16+k)*HH+h],tv,mac[k]);
  }
  #pragma unroll
  for(int k=0;k<16;k++) Mp[(wq*16+k)*64+lane]=mac[k];
}

// ---------------- hyp[n,:] = s[n] * E[n,:] @ M ----------------
__global__ __launch_bounds__(256) void k_hyp2(const float* __restrict__ E,const float* __restrict__ sca,
      const float* __restrict__ Mp,float* __restrict__ hyp,int U){
  __shared__ __align__(16) float es[4][256];
  int tid=threadIdx.x, wave=tid>>6, lane=tid&63;
  float mcol[64];
  #pragma unroll
  for(int j=0;j<64;j++) mcol[j]=Mp[j*64+lane];
  float* esw=es[wave];
  for(int g=blockIdx.x*4+wave; g<U/4; g+=gridDim.x*4){
    int n0=g*4;
    #pragma unroll
    for(int m=0;m<4;m++){
      float sc=sca[n0+m];
      esw[m*64+lane]=E[(size_t)(n0+m)*DD+lane]*sc;
    }
    float acc[4]={0,0,0,0};
    #pragma unroll
    for(int d4=0;d4<16;d4++){
      float4 eb[4];
      #pragma unroll
      for(int m=0;m<4;m++) eb[m]=((const float4*)(esw+m*64))[d4];
      #pragma unroll
      for(int c=0;c<4;c++){
        float mv=mcol[d4*4+c];
        #pragma unroll
        for(int m=0;m<4;m++) acc[m]=fmaf(((const float*)&eb[m])[c],mv,acc[m]);
      }
    }
    #pragma unroll
    for(int m=0;m<4;m++) hyp[(size_t)(n0+m)*DD+lane]=acc[m];
  }
}

// ---------------- dis: in-place z <- LN(z + rec(z)) ----------------
__global__ __launch_bounds__(512) void k_dis(
    float* __restrict__ z,
    const float* __restrict__ W1,const float* __restrict__ b1,
    const float* __restrict__ W2,const float* __restrict__ b2,
    const float* __restrict__ Wr1,const float* __restrict__ br1,
    const float* __restrict__ Wr2,const float* __restrict__ br2,
    const float* __restrict__ wsoft,const float* __restrict__ lng,const float* __restrict__ lnb){
  __shared__ __align__(16) float w1[4*64*64];
  __shared__ __align__(16) float w2[4*64*16];
  __shared__ __align__(16) float wr1[16*64];
  __shared__ __align__(16) float wr2[64*64];
  __shared__ float b1s[256], b2s[64], br1s[64], br2s[64], gs[64], bs[64], sw[4];
  __shared__ __align__(16) float zs[8][4*64];
  __shared__ __align__(16) float hsh[8][4*256];
  __shared__ __align__(16) float cbs[8][4*16];
  __shared__ __align__(16) float r1s[8][4*64];
  int tid=threadIdx.x;
  for(int i=tid;i<4*64*64;i+=512) w1[i]=W1[i];
  for(int i=tid;i<4*64*16;i+=512) w2[i]=W2[i];
  for(int i=tid;i<16*64;i+=512) wr1[i]=Wr1[i];
  for(int i=tid;i<64*64;i+=512) wr2[i]=Wr2[i];
  if(tid<256) b1s[tid]=b1[tid];
  if(tid<64){ b2s[tid]=b2[tid]; br1s[tid]=br1[tid]; br2s[tid]=br2[tid]; gs[tid]=lng[tid]; bs[tid]=lnb[tid]; }
  if(tid==0){
    float m0=fmaxf(fmaxf(wsoft[0],wsoft[1]),fmaxf(wsoft[2],wsoft[3]));
    float e0=expf(wsoft[0]-m0),e1=expf(wsoft[1]-m0),e2=expf(wsoft[2]-m0),e3=expf(wsoft[3]-m0);
    float s=e0+e1+e2+e3;
    sw[0]=e0/s; sw[1]=e1/s; sw[2]=e2/s; sw[3]=e3/s;
  }
  __syncthreads();
  int wave=tid>>6, lane=tid&63;
  int gidx=lane>>4, q=lane&15;
  for(int grp=blockIdx.x*8+wave; grp<NND/4; grp+=gridDim.x*8){
    int n0=grp*4;
    float zr[4];
    #pragma unroll
    for(int m=0;m<4;m++){ zr[m]=z[(size_t)(n0+m)*DD+lane]; zs[wave][m*64+lane]=zr[m]; }
    float ha[4][4];
    #pragma unroll
    for(int k=0;k<4;k++){
      #pragma unroll
      for(int m=0;m<4;m++) ha[k][m]=b1s[k*64+lane];
    }
    for(int d4=0;d4<16;d4++){
      float4 zb[4];
      #pragma unroll
      for(int m=0;m<4;m++) zb[m]=((const float4*)(zs[wave]+m*64))[d4];
      #pragma unroll
      for(int dd=0;dd<4;dd++){
        int d=d4*4+dd;
        #pragma unroll
        for(int k=0;k<4;k++){
          float w=w1[(k*64+d)*64+lane];
          #pragma unroll
          for(int m=0;m<4;m++) ha[k][m]=fmaf(((const float*)&zb[m])[dd], w, ha[k][m]);
        }
      }
    }
    #pragma unroll
    for(int k=0;k<4;k++){
      #pragma unroll
      for(int m=0;m<4;m++) hsh[wave][m*256+k*64+lane]=leaky(ha[k][m]);
    }
    float fa[4];
    #pragma unroll
    for(int m=0;m<4;m++) fa[m]=b2s[gidx*16+q];
    for(int e4=0;e4<16;e4++){
      float4 hb[4];
      #pragma unroll
      for(int m=0;m<4;m++) hb[m]=((const float4*)(hsh[wave]+m*256+gidx*64))[e4];
      #pragma unroll
      for(int ee=0;ee<4;ee++){
        int e=e4*4+ee;
        float w=w2[(gidx*64+e)*16+q];
        #pragma unroll
        for(int m=0;m<4;m++) fa[m]=fmaf(((const float*)&hb[m])[ee], w, fa[m]);
      }
    }
    float swv=sw[gidx];
    #pragma unroll
    for(int m=0;m<4;m++){
      float v=fa[m]*swv;
      v+=__shfl_xor(v,16,64);
      v+=__shfl_xor(v,32,64);
      if(lane<16) cbs[wave][m*16+lane]=v;
    }
    float ra[4];
    #pragma unroll
    for(int m=0;m<4;m++) ra[m]=br1s[lane];
    for(int q4=0;q4<4;q4++){
      float4 cb[4];
      #pragma unroll
      for(int m=0;m<4;m++) cb[m]=((const float4*)(cbs[wave]+m*16))[q4];
      #pragma unroll
      for(int qq=0;qq<4;qq++){
        int qi=q4*4+qq;
        float w=wr1[qi*64+lane];
        #pragma unroll
        for(int m=0;m<4;m++) ra[m]=fmaf(((const float*)&cb[m])[qq], w, ra[m]);
      }
    }
    #pragma unroll
    for(int m=0;m<4;m++) r1s[wave][m*64+lane]=leaky(ra[m]);
    float r2[4];
    #pragma unroll
    for(int m=0;m<4;m++) r2[m]=br2s[lane];
    for(int d4=0;d4<16;d4++){
      float4 rb[4];
      #pragma unroll
      for(int m=0;m<4;m++) rb[m]=((const float4*)(r1s[wave]+m*64))[d4];
      #pragma unroll
      for(int dd=0;dd<4;dd++){
        float w=wr2[(d4*4+dd)*64+lane];
        #pragma unroll
        for(int m=0;m<4;m++) r2[m]=fmaf(((const float*)&rb[m])[dd], w, r2[m]);
      }
    }
    #pragma unroll
    for(int m=0;m<4;m++){
      float y=zr[m]+r2[m];
      float s=y;
      #pragma unroll
      for(int off=32;off;off>>=1) s+=__shfl_xor(s,off,64);
      float mean=s*(1.f/64.f);
      float t=y-mean;
      float s2=t*t;
      #pragma unroll
      for(int off=32;off;off>>=1) s2+=__shfl_xor(s2,off,64);
      float var=s2*(1.f/64.f);
      z[(size_t)(n0+m)*DD+lane]=t*rsqrtf(var+LN_EPS)*gs[lane]+bs[lane];
    }
  }
}

// ---------------- gate core ----------------
__device__ __forceinline__ void gate_core(
    const float* cw, float* s1g, float* s1r,
    const float* wg1, const float* wg2, const float* wr1c, const float* wr2c,
    const float* bg1s,const float* bg2s,const float* br1s,const float* br2s,
    const float* gs, const float* bs,
    const float* cur, int lane, float* yout){
  float ag[4],ar[4];
  #pragma unroll
  for(int m=0;m<4;m++){ ag[m]=bg1s[lane]; ar[m]=br1s[lane]; }
  for(int d4=0;d4<32;d4++){
    float4 cb[4];
    #pragma unroll
    for(int m=0;m<4;m++) cb[m]=((const float4*)(cw+m*128))[d4];
    #pragma unroll
    for(int dd=0;dd<4;dd++){
      int d=d4*4+dd;
      float wg=wg1[d*64+lane], wr=wr1c[d*64+lane];
      #pragma unroll
      for(int m=0;m<4;m++){
        float cv=((const float*)&cb[m])[dd];
        ag[m]=fmaf(cv,wg,ag[m]);
        ar[m]=fmaf(cv,wr,ar[m]);
      }
    }
  }
  #pragma unroll
  for(int m=0;m<4;m++){ s1g[m*64+lane]=fmaxf(ag[m],0.f); s1r[m*64+lane]=leaky(ar[m]); }
  float g2[4],r2[4];
  #pragma unroll
  for(int m=0;m<4;m++){ g2[m]=bg2s[lane]; r2[m]=br2s[lane]; }
  for(int d4=0;d4<16;d4++){
    float4 gb[4],rb[4];
    #pragma unroll
    for(int m=0;m<4;m++){
      gb[m]=((const float4*)(s1g+m*64))[d4];
      rb[m]=((const float4*)(s1r+m*64))[d4];
    }
    #pragma unroll
    for(int dd=0;dd<4;dd++){
      int d=d4*4+dd;
      float wg=wg2[d*64+lane], wr=wr2c[d*64+lane];
      #pragma unroll
      for(int m=0;m<4;m++){
        g2[m]=fmaf(((const float*)&gb[m])[dd],wg,g2[m]);
        r2[m]=fmaf(((const float*)&rb[m])[dd],wr,r2[m]);
      }
    }
  }
  #pragma unroll
  for(int m=0;m<4;m++){
    float gw=1.f/(1.f+expf(-g2[m]));
    float y=gw*r2[m]+cur[m];
    float s=y;
    #pragma unroll
    for(int off=32;off;off>>=1) s+=__shfl_xor(s,off,64);
    float mean=s*(1.f/64.f);
    float t=y-mean;
    float s2=t*t;
    #pragma unroll
    for(int off=32;off;off>>=1) s2+=__shfl_xor(s2,off,64);
    float var=s2*(1.f/64.f);
    yout[m]=t*rsqrtf(var+LN_EPS)*gs[lane]+bs[lane];
  }
}

// ---------------- fused double gate + combine + total accumulate ----------------
__global__ __launch_bounds__(512) void k_gate2(
    float* __restrict__ d0b, float* __restrict__ d1b, float* __restrict__ x, float* __restrict__ out,
    const float* __restrict__ Wg1,const float* __restrict__ bg1,
    const float* __restrict__ Wg2,const float* __restrict__ bg2,
    const float* __restrict__ Wr1,const float* __restrict__ br1,
    const float* __restrict__ Wr2,const float* __restrict__ br2,
    const float* __restrict__ lng,const float* __restrict__ lnb){
  __shared__ __align__(16) float wg1[128*64];
  __shared__ __align__(16) float wg2[64*64];
  __shared__ __align__(16) float wr1[128*64];
  __shared__ __align__(16) float wr2[64*64];
  __shared__ float bg1s[64],bg2s[64],br1s[64],br2s[64],gs[64],bs[64];
  __shared__ __align__(16) float cs[8][4*128];
  __shared__ __align__(16) float s1g[8][4*64];
  __shared__ __align__(16) float s1r[8][4*64];
  int tid=threadIdx.x;
  for(int i=tid;i<128*64;i+=512){ wg1[i]=Wg1[i]; wr1[i]=Wr1[i]; }
  for(int i=tid;i<64*64;i+=512){ wg2[i]=Wg2[i]; wr2[i]=Wr2[i]; }
  if(tid<64){ bg1s[tid]=bg1[tid]; bg2s[tid]=bg2[tid]; br1s[tid]=br1[tid]; br2s[tid]=br2[tid]; gs[tid]=lng[tid]; bs[tid]=lnb[tid]; }
  __syncthreads();
  int wave=tid>>6, lane=tid&63;
  for(int grp=blockIdx.x*8+wave; grp<NND/4; grp+=gridDim.x*8){
    int n0=grp*4;
    float c0[4],c1[4],pv[4];
    #pragma unroll
    for(int m=0;m<4;m++){
      c0[m]=d0b[(size_t)(n0+m)*DD+lane];
      c1[m]=d1b[(size_t)(n0+m)*DD+lane];
      pv[m]=x[(size_t)(n0+m)*DD+lane];
    }
    float* cw=cs[wave];
    #pragma unroll
    for(int m=0;m<4;m++){ cw[m*128+lane]=c0[m]; cw[m*128+64+lane]=pv[m]; }
    float y0[4],y1[4];
    gate_core(cw,s1g[wave],s1r[wave],wg1,wg2,wr1,wr2,bg1s,bg2s,br1s,br2s,gs,bs,c0,lane,y0);
    #pragma unroll
    for(int m=0;m<4;m++){ cw[m*128+lane]=c1[m]; }
    gate_core(cw,s1g[wave],s1r[wave],wg1,wg2,wr1,wr2,bg1s,bg2s,br1s,br2s,gs,bs,c1,lane,y1);
    #pragma unroll
    for(int m=0;m<4;m++){
      float xn=y0[m]+y1[m];
      x[(size_t)(n0+m)*DD+lane]=xn;
      out[(size_t)(n0+m)*DD+lane]+=xn;
    }
  }
}

extern "C" void kernel_launch(void* const* d_in, const int* in_sizes, int n_in,
                              void* d_out, int out_size, void* d_ws, size_t ws_size,
                              hipStream_t stream){
  const float* uE  =(const float*)d_in[0];
  const float* iE  =(const float*)d_in[1];
  const float* uH  =(const float*)d_in[2];
  const float* iH  =(const float*)d_in[3];
  const float* uA  =(const float*)d_in[4];
  const float* iA  =(const float*)d_in[5];
  const float* dW1 =(const float*)d_in[6];
  const float* db1 =(const float*)d_in[7];
  const float* dW2 =(const float*)d_in[8];
  const float* db2 =(const float*)d_in[9];
  const float* dWr1=(const float*)d_in[10];
  const float* dbr1=(const float*)d_in[11];
  const float* dWr2=(const float*)d_in[12];
  const float* dbr2=(const float*)d_in[13];
  const float* dwts=(const float*)d_in[14];
  const float* dlng=(const float*)d_in[15];
  const float* dlnb=(const float*)d_in[16];
  const float* gWg1=(const float*)d_in[17];
  const float* gbg1=(const float*)d_in[18];
  const float* gWg2=(const float*)d_in[19];
  const float* gbg2=(const float*)d_in[20];
  const float* gWr1=(const float*)d_in[21];
  const float* gbr1=(const float*)d_in[22];
  const float* gWr2=(const float*)d_in[23];
  const float* gbr2=(const float*)d_in[24];
  const float* glng=(const float*)d_in[25];
  const float* glnb=(const float*)d_in[26];
  const float* avals=(const float*)d_in[27];
  const int*   arows=(const int*)d_in[28];
  const int*   acols=(const int*)d_in[29];
  float* out=(float*)d_out;
  float* ws =(float*)d_ws;

  // ws layout (floats): x, tem, hyp (3 x N*D), a (N), hv(128), G(2*4096), M(2*4096), red(8)
  size_t need = ((size_t)3*NND*DD + NND + 128 + 8192 + 8192 + 8)*sizeof(float);
  if(ws_size < need) return;  // clean fail (absmax == max|ref|) => ws is the constraint

  float* x   = ws;
  float* tem = x   + (size_t)NND*DD;
  float* hyp = tem + (size_t)NND*DD;
  float* a   = hyp + (size_t)NND*DD;
  float* hv  = a   + NND;
  float* G   = hv  + 128;
  float* Mb  = G   + 8192;
  float* red = Mb  + 8192;

  hipMemsetAsync(red, 0, 8*sizeof(float), stream);
  k_init<<<2048,256,0,stream>>>(uE,iE,x,out);
  k_hv<<<1,128,0,stream>>>(uH,iH,uA,iA,hv);
  k_att<<<256,256,0,stream>>>(uE,hv,a,USERN);
  k_att<<<256,256,0,stream>>>(iE,hv+64,a+USERN,ITEMN);
  k_redmax<<<256,256,0,stream>>>(a,USERN,(unsigned*)red);
  k_redmax<<<256,256,0,stream>>>(a+USERN,ITEMN,(unsigned*)red+2);
  k_sumexp<<<256,256,0,stream>>>(a,USERN,(const unsigned*)red,red+1);
  k_sumexp<<<256,256,0,stream>>>(a+USERN,ITEMN,(const unsigned*)red+2,red+3);
  k_scale_a<<<256,256,0,stream>>>(a,USERN,(const unsigned*)red,red+1);
  k_scale_a<<<256,256,0,stream>>>(a+USERN,ITEMN,(const unsigned*)red+2,red+3);

  for(int i=0;i<2;i++){
    hipMemsetAsync(tem,0,(size_t)NND*DD*sizeof(float),stream);
    k_spmm<<<8192,256,0,stream>>>(avals,arows,acols,x,tem);
    hipMemsetAsync(G,0,8192*sizeof(float),stream);
    k_gacc<<<256,256,0,stream>>>(uE,a,x,G,USERN);
    k_gacc<<<256,256,0,stream>>>(iE,a+USERN,x+(size_t)USERN*DD,G+4096,ITEMN);
    k_tm<<<2,256,0,stream>>>(uH,iH,G,Mb);
    k_hyp2<<<256,256,0,stream>>>(uE,a,Mb,hyp,USERN);
    k_hyp2<<<256,256,0,stream>>>(iE,a+USERN,Mb+4096,hyp+(size_t)USERN*DD,ITEMN);
    for(int j=0;j<2;j++){
      float* zb=(j==0)? tem : hyp;
      int ij=i*2+j;
      k_dis<<<512,512,0,stream>>>(zb,
        dW1+(size_t)ij*4*64*64, db1+(size_t)ij*4*64,
        dW2+(size_t)ij*4*64*16, db2+(size_t)ij*4*16,
        dWr1+(size_t)ij*16*64,  dbr1+(size_t)ij*64,
        dWr2+(size_t)ij*64*64,  dbr2+(size_t)ij*64,
        dwts+(size_t)ij*4, dlng+(size_t)ij*64, dlnb+(size_t)ij*64);
    }
    k_gate2<<<512,512,0,stream>>>(tem,hyp,x,out,
      gWg1+(size_t)i*128*64, gbg1+(size_t)i*64,
      gWg2+(size_t)i*64*64,  gbg2+(size_t)i*64,
      gWr1+(size_t)i*128*64, gbr1+(size_t)i*64,
      gWr2+(size_t)i*64*64,  gbr2+(size_t)i*64,
      glng+(size_t)i*64, glnb+(size_t)i*64);
  }
}

// Round 3
// 11318.192 us; speedup vs baseline: 1.6744x; 1.6744x over previous
//
#include <hip/hip_runtime.h>
#include <math.h>

#define USERN 100000
#define ITEMN 200000
#define NND   300000
#define DD    64
#define HH    128
#define FF    16
#define EDG   3000000
#define LEAKY_A 0.5f
#define LN_EPS  1e-5f

__device__ __forceinline__ float leaky(float x){ return x>0.f ? x : LEAKY_A*x; }
__device__ __forceinline__ unsigned fenc(float f){ unsigned u=__float_as_uint(f); return (u&0x80000000u)? ~u : (u|0x80000000u); }
__device__ __forceinline__ float fdec(unsigned u){ return (u&0x80000000u)? __uint_as_float(u&0x7fffffffu) : __uint_as_float(~u); }
__device__ __forceinline__ float dot4(float4 a, float4 b, float acc){
  acc=fmaf(a.x,b.x,acc); acc=fmaf(a.y,b.y,acc); acc=fmaf(a.z,b.z,acc); acc=fmaf(a.w,b.w,acc); return acc;
}

// ---------------- init: x = concat(uE, iE); out = x ----------------
__global__ __launch_bounds__(256) void k_init(const float* __restrict__ uE, const float* __restrict__ iE,
                        float* __restrict__ x, float* __restrict__ out){
  int tot=NND*DD;
  for(int idx=blockIdx.x*256+threadIdx.x; idx<tot; idx+=gridDim.x*256){
    int n=idx>>6;
    float v=(n<USERN)? uE[idx] : iE[idx-USERN*DD];
    x[idx]=v; out[idx]=v;
  }
}

// ---------------- hv = H @ attn (hv[0:64]=u, hv[64:128]=i) ----------------
__global__ __launch_bounds__(128) void k_hv(const float* __restrict__ uH,const float* __restrict__ iH,
      const float* __restrict__ uA,const float* __restrict__ iA,float* __restrict__ hv){
  int t=threadIdx.x;
  const float* H=(t<64)? uH:iH;
  const float* A=(t<64)? uA:iA;
  int d=t&63;
  float s=0.f;
  for(int h=0;h<HH;h++) s=fmaf(H[d*HH+h],A[h],s);
  hv[t]=s;
}

// ---------------- a[n] = E[n,:] . hv ----------------
__global__ __launch_bounds__(256) void k_att(const float* __restrict__ E, const float* __restrict__ hvp,
      float* __restrict__ a, int U){
  __shared__ float hs[64];
  int tid=threadIdx.x;
  if(tid<64) hs[tid]=hvp[tid];
  __syncthreads();
  int wave=tid>>6, lane=tid&63;
  for(int g=blockIdx.x*4+wave; g<U/4; g+=gridDim.x*4){
    int n0=g*4;
    #pragma unroll
    for(int m=0;m<4;m++){
      float p=E[(size_t)(n0+m)*DD+lane]*hs[lane];
      #pragma unroll
      for(int off=32;off;off>>=1) p+=__shfl_xor(p,off,64);
      if(lane==0) a[n0+m]=p;
    }
  }
}

// ---------------- softmax reductions over node axis ----------------
__global__ __launch_bounds__(256) void k_redmax(const float* __restrict__ a, int n, unsigned* slot){
  float v=-3.0e38f;
  for(int i=blockIdx.x*256+threadIdx.x;i<n;i+=gridDim.x*256) v=fmaxf(v,a[i]);
  #pragma unroll
  for(int off=32;off;off>>=1) v=fmaxf(v,__shfl_xor(v,off,64));
  if((threadIdx.x&63)==0) atomicMax(slot, fenc(v));
}

__global__ __launch_bounds__(256) void k_sumexp(const float* __restrict__ a, int n,
      const unsigned* __restrict__ mslot, float* ssum){
  float mx=fdec(*mslot);
  float s=0.f;
  for(int i=blockIdx.x*256+threadIdx.x;i<n;i+=gridDim.x*256) s+=expf(a[i]-mx);
  #pragma unroll
  for(int off=32;off;off>>=1) s+=__shfl_xor(s,off,64);
  if((threadIdx.x&63)==0) atomicAdd(ssum, s);
}

__global__ __launch_bounds__(256) void k_scale_a(float* __restrict__ a,int n,
      const unsigned* __restrict__ mslot,const float* __restrict__ ssum){
  float mx=fdec(*mslot); float inv=1.f/(*ssum);
  for(int i=blockIdx.x*256+threadIdx.x;i<n;i+=gridDim.x*256) a[i]=expf(a[i]-mx)*inv;
}

// ---------------- SpMM: tem[r,:] += val * x[c,:] (atomic) ----------------
__global__ __launch_bounds__(256) void k_spmm(const float* __restrict__ vals, const int* __restrict__ rows,
      const int* __restrict__ cols, const float* __restrict__ x, float* __restrict__ tem){
  long long tot=(long long)EDG*DD;
  long long stride=(long long)gridDim.x*256;
  for(long long idx=(long long)blockIdx.x*256+threadIdx.x; idx<tot; idx+=stride){
    int e=(int)(idx>>6), d=(int)(idx&63);
    float v=vals[e];
    int r=rows[e], c=cols[e];
    atomicAdd(&tem[(size_t)r*DD+d], v*x[(size_t)c*DD+d]);
  }
}

// ---------------- G[d1,d2] += sum_n s[n]*E[n,d1]*x[n,d2] ----------------
__global__ __launch_bounds__(256) void k_gacc(const float* __restrict__ E,const float* __restrict__ sca,
      const float* __restrict__ x,float* __restrict__ G,int U){
  __shared__ __align__(16) float es[4][256];
  int tid=threadIdx.x, wave=tid>>6, lane=tid&63;
  float acc[64];
  #pragma unroll
  for(int j=0;j<64;j++) acc[j]=0.f;
  float* esw=es[wave];
  for(int g=blockIdx.x*4+wave; g<U/4; g+=gridDim.x*4){
    int n0=g*4;
    float xv[4];
    #pragma unroll
    for(int m=0;m<4;m++){
      float sc=sca[n0+m];
      esw[m*64+lane]=E[(size_t)(n0+m)*DD+lane]*sc;
      xv[m]=x[(size_t)(n0+m)*DD+lane];
    }
    #pragma unroll
    for(int d4=0;d4<16;d4++){
      float4 eb[4];
      #pragma unroll
      for(int m=0;m<4;m++) eb[m]=((const float4*)(esw+m*64))[d4];
      #pragma unroll
      for(int c=0;c<4;c++){
        #pragma unroll
        for(int m=0;m<4;m++) acc[d4*4+c]=fmaf(((const float*)&eb[m])[c],xv[m],acc[d4*4+c]);
      }
    }
  }
  #pragma unroll
  for(int j=0;j<64;j++) atomicAdd(&G[j*64+lane],acc[j]);
}

// ---------------- M = H @ (H^T @ G)  (blockIdx 0=user, 1=item) ----------------
__global__ __launch_bounds__(256) void k_tm(const float* __restrict__ uH,const float* __restrict__ iH,
      const float* __restrict__ G,float* __restrict__ Mo){
  __shared__ __align__(16) float Hs[64*HH];
  __shared__ __align__(16) float Gs[64*64];
  __shared__ __align__(16) float Ts[HH*64];
  const float* H = blockIdx.x ? iH : uH;
  const float* Gp = G + blockIdx.x*4096;
  float* Mp = Mo + blockIdx.x*4096;
  int tid=threadIdx.x;
  for(int k=tid;k<64*HH;k+=256) Hs[k]=H[k];
  for(int k=tid;k<4096;k+=256) Gs[k]=Gp[k];
  __syncthreads();
  int lane=tid&63, wq=tid>>6;
  float tac[32];
  #pragma unroll
  for(int k=0;k<32;k++) tac[k]=0.f;
  for(int d1=0;d1<64;d1++){
    float gv=Gs[d1*64+lane];
    const float4* hrow=(const float4*)(Hs+d1*HH+wq*32);
    #pragma unroll
    for(int k4=0;k4<8;k4++){
      float4 hb=hrow[k4];
      tac[k4*4+0]=fmaf(hb.x,gv,tac[k4*4+0]);
      tac[k4*4+1]=fmaf(hb.y,gv,tac[k4*4+1]);
      tac[k4*4+2]=fmaf(hb.z,gv,tac[k4*4+2]);
      tac[k4*4+3]=fmaf(hb.w,gv,tac[k4*4+3]);
    }
  }
  #pragma unroll
  for(int k=0;k<32;k++) Ts[(wq*32+k)*64+lane]=tac[k];
  __syncthreads();
  float mac[16];
  #pragma unroll
  for(int k=0;k<16;k++) mac[k]=0.f;
  for(int h=0;h<HH;h++){
    float tv=Ts[h*64+lane];
    #pragma unroll
    for(int k=0;k<16;k++) mac[k]=fmaf(Hs[(wq*16+k)*HH+h],tv,mac[k]);
  }
  #pragma unroll
  for(int k=0;k<16;k++) Mp[(wq*16+k)*64+lane]=mac[k];
}

// ---------------- hyp[n,:] = s[n] * E[n,:] @ M ----------------
__global__ __launch_bounds__(256) void k_hyp2(const float* __restrict__ E,const float* __restrict__ sca,
      const float* __restrict__ Mp,float* __restrict__ hyp,int U){
  __shared__ __align__(16) float es[4][256];
  int tid=threadIdx.x, wave=tid>>6, lane=tid&63;
  float mcol[64];
  #pragma unroll
  for(int j=0;j<64;j++) mcol[j]=Mp[j*64+lane];
  float* esw=es[wave];
  for(int g=blockIdx.x*4+wave; g<U/4; g+=gridDim.x*4){
    int n0=g*4;
    #pragma unroll
    for(int m=0;m<4;m++){
      float sc=sca[n0+m];
      esw[m*64+lane]=E[(size_t)(n0+m)*DD+lane]*sc;
    }
    float acc[4]={0,0,0,0};
    #pragma unroll
    for(int d4=0;d4<16;d4++){
      float4 eb[4];
      #pragma unroll
      for(int m=0;m<4;m++) eb[m]=((const float4*)(esw+m*64))[d4];
      #pragma unroll
      for(int c=0;c<4;c++){
        float mv=mcol[d4*4+c];
        #pragma unroll
        for(int m=0;m<4;m++) acc[m]=fmaf(((const float*)&eb[m])[c],mv,acc[m]);
      }
    }
    #pragma unroll
    for(int m=0;m<4;m++) hyp[(size_t)(n0+m)*DD+lane]=acc[m];
  }
}

// ---------------- dis v2: transposed-weight LDS, b128 reads, rolled loops ----------------
// w1t[o][k*64+d] stride 260 ; w2t[lane(k,q)][e] stride 68 ; wr1t[o][q] stride 20 ; wr2t[o][d] stride 68
// hsh[wave][m*272 + k*68 + e]  (k-slot stride 68 kills the 4-way gidx bank alias; z aliased in k=0 slots)
__global__ __launch_bounds__(512) void k_dis(
    float* __restrict__ z,
    const float* __restrict__ W1,const float* __restrict__ b1,
    const float* __restrict__ W2,const float* __restrict__ b2,
    const float* __restrict__ Wr1,const float* __restrict__ br1,
    const float* __restrict__ Wr2,const float* __restrict__ br2,
    const float* __restrict__ wsoft,const float* __restrict__ lng,const float* __restrict__ lnb){
  __shared__ __align__(16) float w1t[64*260];
  __shared__ __align__(16) float w2t[64*68];
  __shared__ __align__(16) float wr1t[64*20];
  __shared__ __align__(16) float wr2t[64*68];
  __shared__ float b1s[256], b2s[64], br1s[64], br2s[64], gs[64], bs[64], sw[4];
  __shared__ __align__(16) float hsh[8][4*272];
  __shared__ __align__(16) float cbs[8][4*16];
  __shared__ __align__(16) float r1s[8][4*64];
  int tid=threadIdx.x;
  // W1: [k][d][o] row-major (k*64+d)*64+o  -> w1t[o*260 + k*64 + d]
  for(int idx=tid;idx<4*64*64;idx+=512){
    int o=idx&63, d=(idx>>6)&63, k=idx>>12;
    w1t[o*260 + k*64 + d]=W1[idx];
  }
  // W2: (k*64+e)*16+q -> w2t[(k*16+q)*68 + e]
  for(int idx=tid;idx<4*64*16;idx+=512){
    int q=idx&15, e=(idx>>4)&63, k=idx>>10;
    w2t[(k*16+q)*68 + e]=W2[idx];
  }
  // Wr1: q*64+o -> wr1t[o*20+q]
  for(int idx=tid;idx<16*64;idx+=512){
    int o=idx&63, q=idx>>6;
    wr1t[o*20+q]=Wr1[idx];
  }
  // Wr2: d*64+o -> wr2t[o*68+d]
  for(int idx=tid;idx<64*64;idx+=512){
    int o=idx&63, d=idx>>6;
    wr2t[o*68+d]=Wr2[idx];
  }
  if(tid<256) b1s[tid]=b1[tid];
  if(tid<64){ b2s[tid]=b2[tid]; br1s[tid]=br1[tid]; br2s[tid]=br2[tid]; gs[tid]=lng[tid]; bs[tid]=lnb[tid]; }
  if(tid==0){
    float m0=fmaxf(fmaxf(wsoft[0],wsoft[1]),fmaxf(wsoft[2],wsoft[3]));
    float e0=expf(wsoft[0]-m0),e1=expf(wsoft[1]-m0),e2=expf(wsoft[2]-m0),e3=expf(wsoft[3]-m0);
    float s=e0+e1+e2+e3;
    sw[0]=e0/s; sw[1]=e1/s; sw[2]=e2/s; sw[3]=e3/s;
  }
  __syncthreads();
  int wave=tid>>6, lane=tid&63;
  int gidx=lane>>4, q=lane&15;
  float* hshw=hsh[wave];
  float* cbsw=cbs[wave];
  float* r1sw=r1s[wave];
  float swv=sw[gidx];
  for(int grp=blockIdx.x*8+wave; grp<NND/4; grp+=gridDim.x*8){
    int n0=grp*4;
    float zr[4];
    #pragma unroll
    for(int m=0;m<4;m++){ zr[m]=z[(size_t)(n0+m)*DD+lane]; hshw[m*272+lane]=zr[m]; }
    // layer1: ha[k][m] = b1 + z @ W1[k]
    float ha[4][4];
    #pragma unroll
    for(int k=0;k<4;k++){
      #pragma unroll
      for(int m=0;m<4;m++) ha[k][m]=b1s[k*64+lane];
    }
    for(int d4=0;d4<16;d4++){
      float4 wv[4];
      #pragma unroll
      for(int k=0;k<4;k++) wv[k]=*(const float4*)&w1t[lane*260 + k*64 + d4*4];
      #pragma unroll
      for(int m=0;m<4;m++){
        float4 cv=*(const float4*)&hshw[m*272 + d4*4];
        #pragma unroll
        for(int k=0;k<4;k++) ha[k][m]=dot4(cv,wv[k],ha[k][m]);
      }
    }
    #pragma unroll
    for(int k=0;k<4;k++){
      #pragma unroll
      for(int m=0;m<4;m++) hshw[m*272 + k*68 + lane]=leaky(ha[k][m]);
    }
    // layer2: fa[m] = b2[gidx] + h[gidx] @ W2[gidx] (lane -> (gidx,q))
    float fa[4];
    #pragma unroll
    for(int m=0;m<4;m++) fa[m]=b2s[gidx*16+q];
    for(int e4=0;e4<16;e4++){
      float4 wv=*(const float4*)&w2t[lane*68 + e4*4];
      #pragma unroll
      for(int m=0;m<4;m++){
        float4 hv=*(const float4*)&hshw[m*272 + gidx*68 + e4*4];
        fa[m]=dot4(hv,wv,fa[m]);
      }
    }
    // comb over k via butterfly
    #pragma unroll
    for(int m=0;m<4;m++){
      float v=fa[m]*swv;
      v+=__shfl_xor(v,16,64);
      v+=__shfl_xor(v,32,64);
      if(lane<16) cbsw[m*16+lane]=v;
    }
    // rec1 = leaky(comb @ Wr1 + br1)
    float ra[4];
    #pragma unroll
    for(int m=0;m<4;m++) ra[m]=br1s[lane];
    for(int q4=0;q4<4;q4++){
      float4 wv=*(const float4*)&wr1t[lane*20 + q4*4];
      #pragma unroll
      for(int m=0;m<4;m++){
        float4 cb=*(const float4*)&cbsw[m*16 + q4*4];
        ra[m]=dot4(cb,wv,ra[m]);
      }
    }
    #pragma unroll
    for(int m=0;m<4;m++) r1sw[m*64+lane]=leaky(ra[m]);
    // rec = rec1 @ Wr2 + br2
    float r2[4];
    #pragma unroll
    for(int m=0;m<4;m++) r2[m]=br2s[lane];
    for(int d4=0;d4<16;d4++){
      float4 wv=*(const float4*)&wr2t[lane*68 + d4*4];
      #pragma unroll
      for(int m=0;m<4;m++){
        float4 rv=*(const float4*)&r1sw[m*64 + d4*4];
        r2[m]=dot4(rv,wv,r2[m]);
      }
    }
    // LN(z + rec)
    #pragma unroll
    for(int m=0;m<4;m++){
      float y=zr[m]+r2[m];
      float s=y;
      #pragma unroll
      for(int off=32;off;off>>=1) s+=__shfl_xor(s,off,64);
      float mean=s*(1.f/64.f);
      float t=y-mean;
      float s2=t*t;
      #pragma unroll
      for(int off=32;off;off>>=1) s2+=__shfl_xor(s2,off,64);
      float var=s2*(1.f/64.f);
      z[(size_t)(n0+m)*DD+lane]=t*rsqrtf(var+LN_EPS)*gs[lane]+bs[lane];
    }
  }
}

// ---------------- gate2 v2: transposed-weight LDS, shared pv-half, rolled loops ----------------
// wg1t/wr1t[o][d] stride 132 (d in 0..127) ; wg2t/wr2t[o][e] stride 68
// cs[wave][m*192 + {c0:0 | c1:64 | pv:128}] ; s1[wave][m*128 + {g:0 | r:64}]
__global__ __launch_bounds__(512) void k_gate2(
    const float* __restrict__ d0b, const float* __restrict__ d1b,
    float* __restrict__ x, float* __restrict__ out,
    const float* __restrict__ Wg1,const float* __restrict__ bg1,
    const float* __restrict__ Wg2,const float* __restrict__ bg2,
    const float* __restrict__ Wr1,const float* __restrict__ br1,
    const float* __restrict__ Wr2,const float* __restrict__ br2,
    const float* __restrict__ lng,const float* __restrict__ lnb){
  __shared__ __align__(16) float wg1t[64*132];
  __shared__ __align__(16) float wr1t[64*132];
  __shared__ __align__(16) float wg2t[64*68];
  __shared__ __align__(16) float wr2t[64*68];
  __shared__ __align__(16) float cs[8][4*192];
  __shared__ __align__(16) float s1[8][4*128];
  __shared__ float bg1s[64],bg2s[64],br1s[64],br2s[64],gs[64],bs[64];
  int tid=threadIdx.x;
  for(int idx=tid; idx<128*64; idx+=512){
    int o=idx&63, d=idx>>6;
    wg1t[o*132+d]=Wg1[idx];
    wr1t[o*132+d]=Wr1[idx];
  }
  for(int idx=tid; idx<64*64; idx+=512){
    int o=idx&63, d=idx>>6;
    wg2t[o*68+d]=Wg2[idx];
    wr2t[o*68+d]=Wr2[idx];
  }
  if(tid<64){ bg1s[tid]=bg1[tid]; bg2s[tid]=bg2[tid]; br1s[tid]=br1[tid]; br2s[tid]=br2[tid]; gs[tid]=lng[tid]; bs[tid]=lnb[tid]; }
  __syncthreads();
  int wave=tid>>6, lane=tid&63;
  float* csw=cs[wave];
  float* s1w=s1[wave];
  for(int grp=blockIdx.x*8+wave; grp<NND/4; grp+=gridDim.x*8){
    int n0=grp*4;
    float c0r[4],c1r[4],pvr[4];
    #pragma unroll
    for(int m=0;m<4;m++){
      c0r[m]=d0b[(size_t)(n0+m)*DD+lane];
      c1r[m]=d1b[(size_t)(n0+m)*DD+lane];
      pvr[m]=x[(size_t)(n0+m)*DD+lane];
    }
    #pragma unroll
    for(int m=0;m<4;m++){
      csw[m*192+lane]=c0r[m];
      csw[m*192+64+lane]=c1r[m];
      csw[m*192+128+lane]=pvr[m];
    }
    // shared pv-half of layer1 (weight rows 64..127), both paths
    float gp[4]={0,0,0,0}, rp[4]={0,0,0,0};
    for(int d4=0;d4<16;d4++){
      float4 wg=*(const float4*)&wg1t[lane*132 + 64 + d4*4];
      float4 wr=*(const float4*)&wr1t[lane*132 + 64 + d4*4];
      #pragma unroll
      for(int m=0;m<4;m++){
        float4 cv=*(const float4*)&csw[m*192 + 128 + d4*4];
        gp[m]=dot4(cv,wg,gp[m]);
        rp[m]=dot4(cv,wr,rp[m]);
      }
    }
    float yA[4], yB[4];
    #pragma unroll
    for(int pass=0; pass<2; pass++){
      int coff = pass ? 64 : 0;
      const float* cur = pass ? c1r : c0r;
      float* yout = pass ? yB : yA;
      float ag[4],ar[4];
      #pragma unroll
      for(int m=0;m<4;m++){ ag[m]=bg1s[lane]+gp[m]; ar[m]=br1s[lane]+rp[m]; }
      for(int d4=0;d4<16;d4++){
        float4 wg=*(const float4*)&wg1t[lane*132 + d4*4];
        float4 wr=*(const float4*)&wr1t[lane*132 + d4*4];
        #pragma unroll
        for(int m=0;m<4;m++){
          float4 cv=*(const float4*)&csw[m*192 + coff + d4*4];
          ag[m]=dot4(cv,wg,ag[m]);
          ar[m]=dot4(cv,wr,ar[m]);
        }
      }
      #pragma unroll
      for(int m=0;m<4;m++){
        s1w[m*128+lane]=fmaxf(ag[m],0.f);
        s1w[m*128+64+lane]=leaky(ar[m]);
      }
      float g2[4],r2[4];
      #pragma unroll
      for(int m=0;m<4;m++){ g2[m]=bg2s[lane]; r2[m]=br2s[lane]; }
      for(int e4=0;e4<16;e4++){
        float4 wg=*(const float4*)&wg2t[lane*68 + e4*4];
        float4 wr=*(const float4*)&wr2t[lane*68 + e4*4];
        #pragma unroll
        for(int m=0;m<4;m++){
          float4 hg=*(const float4*)&s1w[m*128 + e4*4];
          float4 hr=*(const float4*)&s1w[m*128 + 64 + e4*4];
          g2[m]=dot4(hg,wg,g2[m]);
          r2[m]=dot4(hr,wr,r2[m]);
        }
      }
      #pragma unroll
      for(int m=0;m<4;m++){
        float gw=1.f/(1.f+expf(-g2[m]));
        float y=gw*r2[m]+cur[m];
        float s=y;
        #pragma unroll
        for(int off=32;off;off>>=1) s+=__shfl_xor(s,off,64);
        float mean=s*(1.f/64.f);
        float t=y-mean;
        float s2=t*t;
        #pragma unroll
        for(int off=32;off;off>>=1) s2+=__shfl_xor(s2,off,64);
        float var=s2*(1.f/64.f);
        yout[m]=t*rsqrtf(var+LN_EPS)*gs[lane]+bs[lane];
      }
    }
    #pragma unroll
    for(int m=0;m<4;m++){
      float xn=yA[m]+yB[m];
      x[(size_t)(n0+m)*DD+lane]=xn;
      out[(size_t)(n0+m)*DD+lane]+=xn;
    }
  }
}

extern "C" void kernel_launch(void* const* d_in, const int* in_sizes, int n_in,
                              void* d_out, int out_size, void* d_ws, size_t ws_size,
                              hipStream_t stream){
  const float* uE  =(const float*)d_in[0];
  const float* iE  =(const float*)d_in[1];
  const float* uH  =(const float*)d_in[2];
  const float* iH  =(const float*)d_in[3];
  const float* uA  =(const float*)d_in[4];
  const float* iA  =(const float*)d_in[5];
  const float* dW1 =(const float*)d_in[6];
  const float* db1 =(const float*)d_in[7];
  const float* dW2 =(const float*)d_in[8];
  const float* db2 =(const float*)d_in[9];
  const float* dWr1=(const float*)d_in[10];
  const float* dbr1=(const float*)d_in[11];
  const float* dWr2=(const float*)d_in[12];
  const float* dbr2=(const float*)d_in[13];
  const float* dwts=(const float*)d_in[14];
  const float* dlng=(const float*)d_in[15];
  const float* dlnb=(const float*)d_in[16];
  const float* gWg1=(const float*)d_in[17];
  const float* gbg1=(const float*)d_in[18];
  const float* gWg2=(const float*)d_in[19];
  const float* gbg2=(const float*)d_in[20];
  const float* gWr1=(const float*)d_in[21];
  const float* gbr1=(const float*)d_in[22];
  const float* gWr2=(const float*)d_in[23];
  const float* gbr2=(const float*)d_in[24];
  const float* glng=(const float*)d_in[25];
  const float* glnb=(const float*)d_in[26];
  const float* avals=(const float*)d_in[27];
  const int*   arows=(const int*)d_in[28];
  const int*   acols=(const int*)d_in[29];
  float* out=(float*)d_out;
  float* ws =(float*)d_ws;

  size_t need = ((size_t)3*NND*DD + NND + 128 + 8192 + 8192 + 8)*sizeof(float);
  if(ws_size < need) return;

  float* x   = ws;
  float* tem = x   + (size_t)NND*DD;
  float* hyp = tem + (size_t)NND*DD;
  float* a   = hyp + (size_t)NND*DD;
  float* hv  = a   + NND;
  float* G   = hv  + 128;
  float* Mb  = G   + 8192;
  float* red = Mb  + 8192;

  hipMemsetAsync(red, 0, 8*sizeof(float), stream);
  k_init<<<2048,256,0,stream>>>(uE,iE,x,out);
  k_hv<<<1,128,0,stream>>>(uH,iH,uA,iA,hv);
  k_att<<<256,256,0,stream>>>(uE,hv,a,USERN);
  k_att<<<256,256,0,stream>>>(iE,hv+64,a+USERN,ITEMN);
  k_redmax<<<256,256,0,stream>>>(a,USERN,(unsigned*)red);
  k_redmax<<<256,256,0,stream>>>(a+USERN,ITEMN,(unsigned*)red+2);
  k_sumexp<<<256,256,0,stream>>>(a,USERN,(const unsigned*)red,red+1);
  k_sumexp<<<256,256,0,stream>>>(a+USERN,ITEMN,(const unsigned*)red+2,red+3);
  k_scale_a<<<256,256,0,stream>>>(a,USERN,(const unsigned*)red,red+1);
  k_scale_a<<<256,256,0,stream>>>(a+USERN,ITEMN,(const unsigned*)red+2,red+3);

  for(int i=0;i<2;i++){
    hipMemsetAsync(tem,0,(size_t)NND*DD*sizeof(float),stream);
    k_spmm<<<8192,256,0,stream>>>(avals,arows,acols,x,tem);
    hipMemsetAsync(G,0,8192*sizeof(float),stream);
    k_gacc<<<256,256,0,stream>>>(uE,a,x,G,USERN);
    k_gacc<<<256,256,0,stream>>>(iE,a+USERN,x+(size_t)USERN*DD,G+4096,ITEMN);
    k_tm<<<2,256,0,stream>>>(uH,iH,G,Mb);
    k_hyp2<<<256,256,0,stream>>>(uE,a,Mb,hyp,USERN);
    k_hyp2<<<256,256,0,stream>>>(iE,a+USERN,Mb+4096,hyp+(size_t)USERN*DD,ITEMN);
    for(int j=0;j<2;j++){
      float* zb=(j==0)? tem : hyp;
      int ij=i*2+j;
      k_dis<<<512,512,0,stream>>>(zb,
        dW1+(size_t)ij*4*64*64, db1+(size_t)ij*4*64,
        dW2+(size_t)ij*4*64*16, db2+(size_t)ij*4*16,
        dWr1+(size_t)ij*16*64,  dbr1+(size_t)ij*64,
        dWr2+(size_t)ij*64*64,  dbr2+(size_t)ij*64,
        dwts+(size_t)ij*4, dlng+(size_t)ij*64, dlnb+(size_t)ij*64);
    }
    k_gate2<<<512,512,0,stream>>>(tem,hyp,x,out,
      gWg1+(size_t)i*128*64, gbg1+(size_t)i*64,
      gWg2+(size_t)i*64*64,  gbg2+(size_t)i*64,
      gWr1+(size_t)i*128*64, gbr1+(size_t)i*64,
      gWr2+(size_t)i*64*64,  gbr2+(size_t)i*64,
      glng+(size_t)i*64, glnb+(size_t)i*64);
  }
}

// Round 4
// 6418.746 us; speedup vs baseline: 2.9525x; 1.7633x over previous
//
#include <hip/hip_runtime.h>
#include <math.h>

#define USERN 100000
#define ITEMN 200000
#define NND   300000
#define DD    64
#define HH    128
#define FF    16
#define EDG   3000000
#define LEAKY_A 0.5f
#define LN_EPS  1e-5f

typedef __attribute__((ext_vector_type(8))) short bf16x8;
typedef __attribute__((ext_vector_type(4))) float f32x4;
#define MFMA16(a,b,c) __builtin_amdgcn_mfma_f32_16x16x32_bf16(a,b,c,0,0,0)

__device__ __forceinline__ float leaky(float x){ return x>0.f ? x : LEAKY_A*x; }
__device__ __forceinline__ unsigned fenc(float f){ unsigned u=__float_as_uint(f); return (u&0x80000000u)? ~u : (u|0x80000000u); }
__device__ __forceinline__ float fdec(unsigned u){ return (u&0x80000000u)? __uint_as_float(u&0x7fffffffu) : __uint_as_float(~u); }
__device__ __forceinline__ float dot4(float4 a, float4 b, float acc){
  acc=fmaf(a.x,b.x,acc); acc=fmaf(a.y,b.y,acc); acc=fmaf(a.z,b.z,acc); acc=fmaf(a.w,b.w,acc); return acc;
}
// f32 -> bf16 bits, round-nearest-even
__device__ __forceinline__ short f2bf(float f){
  unsigned u=__float_as_uint(f);
  unsigned r=u + 0x7fffu + ((u>>16)&1u);
  return (short)(r>>16);
}
// A-frag loader: lane l supplies row (l&15), k-slots j=0..3 -> dbase+(l>>4)*4+j, j=4..7 -> +16
__device__ __forceinline__ bf16x8 loadA(const float* __restrict__ base, int l, int dbase){
  const float* p = base + (size_t)(l&15)*DD + dbase + ((l>>4)<<2);
  float4 a=*(const float4*)p;
  float4 b=*(const float4*)(p+16);
  bf16x8 r;
  r[0]=f2bf(a.x); r[1]=f2bf(a.y); r[2]=f2bf(a.z); r[3]=f2bf(a.w);
  r[4]=f2bf(b.x); r[5]=f2bf(b.y); r[6]=f2bf(b.z); r[7]=f2bf(b.w);
  return r;
}

// ---------------- init: x = concat(uE, iE); out = x ----------------
__global__ __launch_bounds__(256) void k_init(const float* __restrict__ uE, const float* __restrict__ iE,
                        float* __restrict__ x, float* __restrict__ out){
  int tot=NND*DD;
  for(int idx=blockIdx.x*256+threadIdx.x; idx<tot; idx+=gridDim.x*256){
    int n=idx>>6;
    float v=(n<USERN)? uE[idx] : iE[idx-USERN*DD];
    x[idx]=v; out[idx]=v;
  }
}

// ---------------- hv = H @ attn (hv[0:64]=u, hv[64:128]=i) ----------------
__global__ __launch_bounds__(128) void k_hv(const float* __restrict__ uH,const float* __restrict__ iH,
      const float* __restrict__ uA,const float* __restrict__ iA,float* __restrict__ hv){
  int t=threadIdx.x;
  const float* H=(t<64)? uH:iH;
  const float* A=(t<64)? uA:iA;
  int d=t&63;
  float s=0.f;
  for(int h=0;h<HH;h++) s=fmaf(H[d*HH+h],A[h],s);
  hv[t]=s;
}

// ---------------- a[n] = E[n,:] . hv ----------------
__global__ __launch_bounds__(256) void k_att(const float* __restrict__ E, const float* __restrict__ hvp,
      float* __restrict__ a, int U){
  __shared__ float hs[64];
  int tid=threadIdx.x;
  if(tid<64) hs[tid]=hvp[tid];
  __syncthreads();
  int wave=tid>>6, lane=tid&63;
  for(int g=blockIdx.x*4+wave; g<U/4; g+=gridDim.x*4){
    int n0=g*4;
    #pragma unroll
    for(int m=0;m<4;m++){
      float p=E[(size_t)(n0+m)*DD+lane]*hs[lane];
      #pragma unroll
      for(int off=32;off;off>>=1) p+=__shfl_xor(p,off,64);
      if(lane==0) a[n0+m]=p;
    }
  }
}

// ---------------- softmax reductions over node axis ----------------
__global__ __launch_bounds__(256) void k_redmax(const float* __restrict__ a, int n, unsigned* slot){
  float v=-3.0e38f;
  for(int i=blockIdx.x*256+threadIdx.x;i<n;i+=gridDim.x*256) v=fmaxf(v,a[i]);
  #pragma unroll
  for(int off=32;off;off>>=1) v=fmaxf(v,__shfl_xor(v,off,64));
  if((threadIdx.x&63)==0) atomicMax(slot, fenc(v));
}

__global__ __launch_bounds__(256) void k_sumexp(const float* __restrict__ a, int n,
      const unsigned* __restrict__ mslot, float* ssum){
  float mx=fdec(*mslot);
  float s=0.f;
  for(int i=blockIdx.x*256+threadIdx.x;i<n;i+=gridDim.x*256) s+=expf(a[i]-mx);
  #pragma unroll
  for(int off=32;off;off>>=1) s+=__shfl_xor(s,off,64);
  if((threadIdx.x&63)==0) atomicAdd(ssum, s);
}

__global__ __launch_bounds__(256) void k_scale_a(float* __restrict__ a,int n,
      const unsigned* __restrict__ mslot,const float* __restrict__ ssum){
  float mx=fdec(*mslot); float inv=1.f/(*ssum);
  for(int i=blockIdx.x*256+threadIdx.x;i<n;i+=gridDim.x*256) a[i]=expf(a[i]-mx)*inv;
}

// ---------------- SpMM: tem[r,:] += val * x[c,:] (atomic) ----------------
__global__ __launch_bounds__(256) void k_spmm(const float* __restrict__ vals, const int* __restrict__ rows,
      const int* __restrict__ cols, const float* __restrict__ x, float* __restrict__ tem){
  long long tot=(long long)EDG*DD;
  long long stride=(long long)gridDim.x*256;
  for(long long idx=(long long)blockIdx.x*256+threadIdx.x; idx<tot; idx+=stride){
    int e=(int)(idx>>6), d=(int)(idx&63);
    float v=vals[e];
    int r=rows[e], c=cols[e];
    atomicAdd(&tem[(size_t)r*DD+d], v*x[(size_t)c*DD+d]);
  }
}

// ---------------- G[d1,d2] += sum_n s[n]*E[n,d1]*x[n,d2] ----------------
__global__ __launch_bounds__(256) void k_gacc(const float* __restrict__ E,const float* __restrict__ sca,
      const float* __restrict__ x,float* __restrict__ G,int U){
  __shared__ __align__(16) float es[4][256];
  int tid=threadIdx.x, wave=tid>>6, lane=tid&63;
  float acc[64];
  #pragma unroll
  for(int j=0;j<64;j++) acc[j]=0.f;
  float* esw=es[wave];
  for(int g=blockIdx.x*4+wave; g<U/4; g+=gridDim.x*4){
    int n0=g*4;
    float xv[4];
    #pragma unroll
    for(int m=0;m<4;m++){
      float sc=sca[n0+m];
      esw[m*64+lane]=E[(size_t)(n0+m)*DD+lane]*sc;
      xv[m]=x[(size_t)(n0+m)*DD+lane];
    }
    #pragma unroll
    for(int d4=0;d4<16;d4++){
      float4 eb[4];
      #pragma unroll
      for(int m=0;m<4;m++) eb[m]=((const float4*)(esw+m*64))[d4];
      #pragma unroll
      for(int c=0;c<4;c++){
        #pragma unroll
        for(int m=0;m<4;m++) acc[d4*4+c]=fmaf(((const float*)&eb[m])[c],xv[m],acc[d4*4+c]);
      }
    }
  }
  #pragma unroll
  for(int j=0;j<64;j++) atomicAdd(&G[j*64+lane],acc[j]);
}

// ---------------- M = H @ (H^T @ G)  (blockIdx 0=user, 1=item) ----------------
__global__ __launch_bounds__(256) void k_tm(const float* __restrict__ uH,const float* __restrict__ iH,
      const float* __restrict__ G,float* __restrict__ Mo){
  __shared__ __align__(16) float Hs[64*HH];
  __shared__ __align__(16) float Gs[64*64];
  __shared__ __align__(16) float Ts[HH*64];
  const float* H = blockIdx.x ? iH : uH;
  const float* Gp = G + blockIdx.x*4096;
  float* Mp = Mo + blockIdx.x*4096;
  int tid=threadIdx.x;
  for(int k=tid;k<64*HH;k+=256) Hs[k]=H[k];
  for(int k=tid;k<4096;k+=256) Gs[k]=Gp[k];
  __syncthreads();
  int lane=tid&63, wq=tid>>6;
  float tac[32];
  #pragma unroll
  for(int k=0;k<32;k++) tac[k]=0.f;
  for(int d1=0;d1<64;d1++){
    float gv=Gs[d1*64+lane];
    const float4* hrow=(const float4*)(Hs+d1*HH+wq*32);
    #pragma unroll
    for(int k4=0;k4<8;k4++){
      float4 hb=hrow[k4];
      tac[k4*4+0]=fmaf(hb.x,gv,tac[k4*4+0]);
      tac[k4*4+1]=fmaf(hb.y,gv,tac[k4*4+1]);
      tac[k4*4+2]=fmaf(hb.z,gv,tac[k4*4+2]);
      tac[k4*4+3]=fmaf(hb.w,gv,tac[k4*4+3]);
    }
  }
  #pragma unroll
  for(int k=0;k<32;k++) Ts[(wq*32+k)*64+lane]=tac[k];
  __syncthreads();
  float mac[16];
  #pragma unroll
  for(int k=0;k<16;k++) mac[k]=0.f;
  for(int h=0;h<HH;h++){
    float tv=Ts[h*64+lane];
    #pragma unroll
    for(int k=0;k<16;k++) mac[k]=fmaf(Hs[(wq*16+k)*HH+h],tv,mac[k]);
  }
  #pragma unroll
  for(int k=0;k<16;k++) Mp[(wq*16+k)*64+lane]=mac[k];
}

// ---------------- hyp[n,:] = s[n] * E[n,:] @ M ----------------
__global__ __launch_bounds__(256) void k_hyp2(const float* __restrict__ E,const float* __restrict__ sca,
      const float* __restrict__ Mp,float* __restrict__ hyp,int U){
  __shared__ __align__(16) float es[4][256];
  int tid=threadIdx.x, wave=tid>>6, lane=tid&63;
  float mcol[64];
  #pragma unroll
  for(int j=0;j<64;j++) mcol[j]=Mp[j*64+lane];
  float* esw=es[wave];
  for(int g=blockIdx.x*4+wave; g<U/4; g+=gridDim.x*4){
    int n0=g*4;
    #pragma unroll
    for(int m=0;m<4;m++){
      float sc=sca[n0+m];
      esw[m*64+lane]=E[(size_t)(n0+m)*DD+lane]*sc;
    }
    float acc[4]={0,0,0,0};
    #pragma unroll
    for(int d4=0;d4<16;d4++){
      float4 eb[4];
      #pragma unroll
      for(int m=0;m<4;m++) eb[m]=((const float4*)(esw+m*64))[d4];
      #pragma unroll
      for(int c=0;c<4;c++){
        float mv=mcol[d4*4+c];
        #pragma unroll
        for(int m=0;m<4;m++) acc[m]=fmaf(((const float*)&eb[m])[c],mv,acc[m]);
      }
    }
    #pragma unroll
    for(int m=0;m<4;m++) hyp[(size_t)(n0+m)*DD+lane]=acc[m];
  }
}

// ---------------- dis (f32, unchanged from round 3) ----------------
__global__ __launch_bounds__(512) void k_dis(
    float* __restrict__ z,
    const float* __restrict__ W1,const float* __restrict__ b1,
    const float* __restrict__ W2,const float* __restrict__ b2,
    const float* __restrict__ Wr1,const float* __restrict__ br1,
    const float* __restrict__ Wr2,const float* __restrict__ br2,
    const float* __restrict__ wsoft,const float* __restrict__ lng,const float* __restrict__ lnb){
  __shared__ __align__(16) float w1t[64*260];
  __shared__ __align__(16) float w2t[64*68];
  __shared__ __align__(16) float wr1t[64*20];
  __shared__ __align__(16) float wr2t[64*68];
  __shared__ float b1s[256], b2s[64], br1s[64], br2s[64], gs[64], bs[64], sw[4];
  __shared__ __align__(16) float hsh[8][4*272];
  __shared__ __align__(16) float cbs[8][4*16];
  __shared__ __align__(16) float r1s[8][4*64];
  int tid=threadIdx.x;
  for(int idx=tid;idx<4*64*64;idx+=512){
    int o=idx&63, d=(idx>>6)&63, k=idx>>12;
    w1t[o*260 + k*64 + d]=W1[idx];
  }
  for(int idx=tid;idx<4*64*16;idx+=512){
    int q=idx&15, e=(idx>>4)&63, k=idx>>10;
    w2t[(k*16+q)*68 + e]=W2[idx];
  }
  for(int idx=tid;idx<16*64;idx+=512){
    int o=idx&63, q=idx>>6;
    wr1t[o*20+q]=Wr1[idx];
  }
  for(int idx=tid;idx<64*64;idx+=512){
    int o=idx&63, d=idx>>6;
    wr2t[o*68+d]=Wr2[idx];
  }
  if(tid<256) b1s[tid]=b1[tid];
  if(tid<64){ b2s[tid]=b2[tid]; br1s[tid]=br1[tid]; br2s[tid]=br2[tid]; gs[tid]=lng[tid]; bs[tid]=lnb[tid]; }
  if(tid==0){
    float m0=fmaxf(fmaxf(wsoft[0],wsoft[1]),fmaxf(wsoft[2],wsoft[3]));
    float e0=expf(wsoft[0]-m0),e1=expf(wsoft[1]-m0),e2=expf(wsoft[2]-m0),e3=expf(wsoft[3]-m0);
    float s=e0+e1+e2+e3;
    sw[0]=e0/s; sw[1]=e1/s; sw[2]=e2/s; sw[3]=e3/s;
  }
  __syncthreads();
  int wave=tid>>6, lane=tid&63;
  int gidx=lane>>4, q=lane&15;
  float* hshw=hsh[wave];
  float* cbsw=cbs[wave];
  float* r1sw=r1s[wave];
  float swv=sw[gidx];
  for(int grp=blockIdx.x*8+wave; grp<NND/4; grp+=gridDim.x*8){
    int n0=grp*4;
    float zr[4];
    #pragma unroll
    for(int m=0;m<4;m++){ zr[m]=z[(size_t)(n0+m)*DD+lane]; hshw[m*272+lane]=zr[m]; }
    float ha[4][4];
    #pragma unroll
    for(int k=0;k<4;k++){
      #pragma unroll
      for(int m=0;m<4;m++) ha[k][m]=b1s[k*64+lane];
    }
    for(int d4=0;d4<16;d4++){
      float4 wv[4];
      #pragma unroll
      for(int k=0;k<4;k++) wv[k]=*(const float4*)&w1t[lane*260 + k*64 + d4*4];
      #pragma unroll
      for(int m=0;m<4;m++){
        float4 cv=*(const float4*)&hshw[m*272 + d4*4];
        #pragma unroll
        for(int k=0;k<4;k++) ha[k][m]=dot4(cv,wv[k],ha[k][m]);
      }
    }
    #pragma unroll
    for(int k=0;k<4;k++){
      #pragma unroll
      for(int m=0;m<4;m++) hshw[m*272 + k*68 + lane]=leaky(ha[k][m]);
    }
    float fa[4];
    #pragma unroll
    for(int m=0;m<4;m++) fa[m]=b2s[gidx*16+q];
    for(int e4=0;e4<16;e4++){
      float4 wv=*(const float4*)&w2t[lane*68 + e4*4];
      #pragma unroll
      for(int m=0;m<4;m++){
        float4 hv=*(const float4*)&hshw[m*272 + gidx*68 + e4*4];
        fa[m]=dot4(hv,wv,fa[m]);
      }
    }
    #pragma unroll
    for(int m=0;m<4;m++){
      float v=fa[m]*swv;
      v+=__shfl_xor(v,16,64);
      v+=__shfl_xor(v,32,64);
      if(lane<16) cbsw[m*16+lane]=v;
    }
    float ra[4];
    #pragma unroll
    for(int m=0;m<4;m++) ra[m]=br1s[lane];
    for(int q4=0;q4<4;q4++){
      float4 wv=*(const float4*)&wr1t[lane*20 + q4*4];
      #pragma unroll
      for(int m=0;m<4;m++){
        float4 cb=*(const float4*)&cbsw[m*16 + q4*4];
        ra[m]=dot4(cb,wv,ra[m]);
      }
    }
    #pragma unroll
    for(int m=0;m<4;m++) r1sw[m*64+lane]=leaky(ra[m]);
    float r2[4];
    #pragma unroll
    for(int m=0;m<4;m++) r2[m]=br2s[lane];
    for(int d4=0;d4<16;d4++){
      float4 wv=*(const float4*)&wr2t[lane*68 + d4*4];
      #pragma unroll
      for(int m=0;m<4;m++){
        float4 rv=*(const float4*)&r1sw[m*64 + d4*4];
        r2[m]=dot4(rv,wv,r2[m]);
      }
    }
    #pragma unroll
    for(int m=0;m<4;m++){
      float y=zr[m]+r2[m];
      float s=y;
      #pragma unroll
      for(int off=32;off;off>>=1) s+=__shfl_xor(s,off,64);
      float mean=s*(1.f/64.f);
      float t=y-mean;
      float s2=t*t;
      #pragma unroll
      for(int off=32;off;off>>=1) s2+=__shfl_xor(s2,off,64);
      float var=s2*(1.f/64.f);
      z[(size_t)(n0+m)*DD+lane]=t*rsqrtf(var+LN_EPS)*gs[lane]+bs[lane];
    }
  }
}

// ---------------- gate2 v3: bf16 MFMA 16x16x32, 16 nodes/wave ----------------
// Weight B-frag LDS layout: region(kblk,ot) of 512 bf16; slot s=(c*4+kg)*8+j';
// k = kblk*32 + kg*4 + (j'&3) + ((j'>>2)<<4)   (self-chosen k-map, same for A and B)
// D-frag: row=(l>>4)*4+j, col=l&15 (HW-verified).
__global__ __launch_bounds__(512) void k_gate2(
    const float* __restrict__ tem, const float* __restrict__ hyp,
    float* __restrict__ x, float* __restrict__ out,
    const float* __restrict__ Wg1,const float* __restrict__ bg1,
    const float* __restrict__ Wg2,const float* __restrict__ bg2,
    const float* __restrict__ Wr1,const float* __restrict__ br1,
    const float* __restrict__ Wr2,const float* __restrict__ br2,
    const float* __restrict__ lng,const float* __restrict__ lnb){
  __shared__ __align__(16) short g1s[4*4*512];   // Wg1 [128x64]
  __shared__ __align__(16) short r1s[4*4*512];   // Wr1
  __shared__ __align__(16) short g2s[2*4*512];   // Wg2 [64x64]
  __shared__ __align__(16) short r2s[2*4*512];   // Wr2
  __shared__ __align__(16) short hls[8][2][1024];// per-wave h (g,r): 2 kblk x 512
  int tid=threadIdx.x;
  for(int t=tid;t<8192;t+=512){
    int j=t&7,kg=(t>>3)&3,c=(t>>5)&15,ot=(t>>9)&3,kb=t>>11;
    int k=kb*32+kg*4+(j&3)+((j>>2)<<4), o=ot*16+c;
    g1s[t]=f2bf(Wg1[k*64+o]);
    r1s[t]=f2bf(Wr1[k*64+o]);
  }
  for(int t=tid;t<4096;t+=512){
    int j=t&7,kg=(t>>3)&3,c=(t>>5)&15,ot=(t>>9)&3,kb=t>>11;
    int k=kb*32+kg*4+(j&3)+((j>>2)<<4), o=ot*16+c;
    g2s[t]=f2bf(Wg2[k*64+o]);
    r2s[t]=f2bf(Wr2[k*64+o]);
  }
  __syncthreads();
  int wave=tid>>6, l=tid&63;
  int lr=l&15, lg=l>>4;
  float bg1v[4],br1v[4],bg2v[4],br2v[4],gv[4],bv[4];
  #pragma unroll
  for(int ot=0;ot<4;ot++){
    bg1v[ot]=bg1[ot*16+lr]; br1v[ot]=br1[ot*16+lr];
    bg2v[ot]=bg2[ot*16+lr]; br2v[ot]=br2[ot*16+lr];
    gv[ot]=lng[ot*16+lr];   bv[ot]=lnb[ot*16+lr];
  }
  short* hG=&hls[wave][0][0];
  short* hR=&hls[wave][1][0];
  int slot=(lr*4+lg)*8;
  const f32x4 zero={0.f,0.f,0.f,0.f};
  for(int tile=blockIdx.x*8+wave; tile<NND/16; tile+=gridDim.x*8){
    int n0=tile*16;
    const float* xrow=x+(size_t)n0*DD;
    // prev (x) A-frags + pass-independent half of layer1
    bf16x8 pA0=loadA(xrow,l,0), pA1=loadA(xrow,l,32);
    f32x4 pg[4],pr[4];
    #pragma unroll
    for(int ot=0;ot<4;ot++){
      f32x4 ag=zero, ar=zero;
      ag=MFMA16(pA0,*(const bf16x8*)&g1s[(2*4+ot)*512+slot],ag);
      ag=MFMA16(pA1,*(const bf16x8*)&g1s[(3*4+ot)*512+slot],ag);
      ar=MFMA16(pA0,*(const bf16x8*)&r1s[(2*4+ot)*512+slot],ar);
      ar=MFMA16(pA1,*(const bf16x8*)&r1s[(3*4+ot)*512+slot],ar);
      pg[ot]=ag; pr[ot]=ar;
    }
    float ya[4][4];
    #pragma unroll
    for(int p=0;p<2;p++){
      const float* cur=(p? hyp : tem)+(size_t)n0*DD;
      bf16x8 cA0=loadA(cur,l,0), cA1=loadA(cur,l,32);
      // layer1 + act -> h in LDS (A-slot layout)
      #pragma unroll
      for(int ot=0;ot<4;ot++){
        f32x4 ag=pg[ot], ar=pr[ot];
        ag=MFMA16(cA0,*(const bf16x8*)&g1s[(0*4+ot)*512+slot],ag);
        ag=MFMA16(cA1,*(const bf16x8*)&g1s[(1*4+ot)*512+slot],ag);
        ar=MFMA16(cA0,*(const bf16x8*)&r1s[(0*4+ot)*512+slot],ar);
        ar=MFMA16(cA1,*(const bf16x8*)&r1s[(1*4+ot)*512+slot],ar);
        int kb2=ot>>1;
        #pragma unroll
        for(int j=0;j<4;j++){
          int addr=kb2*512 + ((lg*4+j)*4 + (lr>>2))*8 + ((ot&1)<<2) + (l&3);
          hG[addr]=f2bf(fmaxf(ag[j]+bg1v[ot],0.f));
          hR[addr]=f2bf(leaky(ar[j]+br1v[ot]));
        }
      }
      // layer2
      bf16x8 hgA0=*(const bf16x8*)&hG[slot],    hgA1=*(const bf16x8*)&hG[512+slot];
      bf16x8 hrA0=*(const bf16x8*)&hR[slot],    hrA1=*(const bf16x8*)&hR[512+slot];
      f32x4 g2a[4], r2a[4];
      #pragma unroll
      for(int ot=0;ot<4;ot++){
        f32x4 ag=zero, ar=zero;
        ag=MFMA16(hgA0,*(const bf16x8*)&g2s[(0*4+ot)*512+slot],ag);
        ag=MFMA16(hgA1,*(const bf16x8*)&g2s[(1*4+ot)*512+slot],ag);
        ar=MFMA16(hrA0,*(const bf16x8*)&r2s[(0*4+ot)*512+slot],ar);
        ar=MFMA16(hrA1,*(const bf16x8*)&r2s[(1*4+ot)*512+slot],ar);
        g2a[ot]=ag; r2a[ot]=ar;
      }
      // epilogue: sigmoid gate, residual, LN  (D layout: row=lg*4+j, col=ot*16+lr)
      float y[4][4];
      #pragma unroll
      for(int ot=0;ot<4;ot++){
        #pragma unroll
        for(int j=0;j<4;j++){
          float cd=cur[(size_t)(lg*4+j)*DD + ot*16+lr];
          float gw=1.f/(1.f+expf(-(g2a[ot][j]+bg2v[ot])));
          y[ot][j]=gw*(r2a[ot][j]+br2v[ot])+cd;
        }
      }
      #pragma unroll
      for(int j=0;j<4;j++){
        float s=y[0][j]+y[1][j]+y[2][j]+y[3][j];
        s+=__shfl_xor(s,1,64); s+=__shfl_xor(s,2,64); s+=__shfl_xor(s,4,64); s+=__shfl_xor(s,8,64);
        float mean=s*(1.f/64.f);
        float t0=y[0][j]-mean, t1=y[1][j]-mean, t2=y[2][j]-mean, t3=y[3][j]-mean;
        float s2=t0*t0+t1*t1+t2*t2+t3*t3;
        s2+=__shfl_xor(s2,1,64); s2+=__shfl_xor(s2,2,64); s2+=__shfl_xor(s2,4,64); s2+=__shfl_xor(s2,8,64);
        float inv=rsqrtf(s2*(1.f/64.f)+LN_EPS);
        float yn0=t0*inv*gv[0]+bv[0];
        float yn1=t1*inv*gv[1]+bv[1];
        float yn2=t2*inv*gv[2]+bv[2];
        float yn3=t3*inv*gv[3]+bv[3];
        if(p==0){ ya[0][j]=yn0; ya[1][j]=yn1; ya[2][j]=yn2; ya[3][j]=yn3; }
        else    { ya[0][j]+=yn0; ya[1][j]+=yn1; ya[2][j]+=yn2; ya[3][j]+=yn3; }
      }
    }
    #pragma unroll
    for(int ot=0;ot<4;ot++){
      #pragma unroll
      for(int j=0;j<4;j++){
        size_t idx=(size_t)(n0+lg*4+j)*DD + ot*16+lr;
        x[idx]=ya[ot][j];
        out[idx]+=ya[ot][j];
      }
    }
  }
}

extern "C" void kernel_launch(void* const* d_in, const int* in_sizes, int n_in,
                              void* d_out, int out_size, void* d_ws, size_t ws_size,
                              hipStream_t stream){
  const float* uE  =(const float*)d_in[0];
  const float* iE  =(const float*)d_in[1];
  const float* uH  =(const float*)d_in[2];
  const float* iH  =(const float*)d_in[3];
  const float* uA  =(const float*)d_in[4];
  const float* iA  =(const float*)d_in[5];
  const float* dW1 =(const float*)d_in[6];
  const float* db1 =(const float*)d_in[7];
  const float* dW2 =(const float*)d_in[8];
  const float* db2 =(const float*)d_in[9];
  const float* dWr1=(const float*)d_in[10];
  const float* dbr1=(const float*)d_in[11];
  const float* dWr2=(const float*)d_in[12];
  const float* dbr2=(const float*)d_in[13];
  const float* dwts=(const float*)d_in[14];
  const float* dlng=(const float*)d_in[15];
  const float* dlnb=(const float*)d_in[16];
  const float* gWg1=(const float*)d_in[17];
  const float* gbg1=(const float*)d_in[18];
  const float* gWg2=(const float*)d_in[19];
  const float* gbg2=(const float*)d_in[20];
  const float* gWr1=(const float*)d_in[21];
  const float* gbr1=(const float*)d_in[22];
  const float* gWr2=(const float*)d_in[23];
  const float* gbr2=(const float*)d_in[24];
  const float* glng=(const float*)d_in[25];
  const float* glnb=(const float*)d_in[26];
  const float* avals=(const float*)d_in[27];
  const int*   arows=(const int*)d_in[28];
  const int*   acols=(const int*)d_in[29];
  float* out=(float*)d_out;
  float* ws =(float*)d_ws;

  size_t need = ((size_t)3*NND*DD + NND + 128 + 8192 + 8192 + 8)*sizeof(float);
  if(ws_size < need) return;

  float* x   = ws;
  float* tem = x   + (size_t)NND*DD;
  float* hyp = tem + (size_t)NND*DD;
  float* a   = hyp + (size_t)NND*DD;
  float* hv  = a   + NND;
  float* G   = hv  + 128;
  float* Mb  = G   + 8192;
  float* red = Mb  + 8192;

  hipMemsetAsync(red, 0, 8*sizeof(float), stream);
  k_init<<<2048,256,0,stream>>>(uE,iE,x,out);
  k_hv<<<1,128,0,stream>>>(uH,iH,uA,iA,hv);
  k_att<<<256,256,0,stream>>>(uE,hv,a,USERN);
  k_att<<<256,256,0,stream>>>(iE,hv+64,a+USERN,ITEMN);
  k_redmax<<<256,256,0,stream>>>(a,USERN,(unsigned*)red);
  k_redmax<<<256,256,0,stream>>>(a+USERN,ITEMN,(unsigned*)red+2);
  k_sumexp<<<256,256,0,stream>>>(a,USERN,(const unsigned*)red,red+1);
  k_sumexp<<<256,256,0,stream>>>(a+USERN,ITEMN,(const unsigned*)red+2,red+3);
  k_scale_a<<<256,256,0,stream>>>(a,USERN,(const unsigned*)red,red+1);
  k_scale_a<<<256,256,0,stream>>>(a+USERN,ITEMN,(const unsigned*)red+2,red+3);

  for(int i=0;i<2;i++){
    hipMemsetAsync(tem,0,(size_t)NND*DD*sizeof(float),stream);
    k_spmm<<<8192,256,0,stream>>>(avals,arows,acols,x,tem);
    hipMemsetAsync(G,0,8192*sizeof(float),stream);
    k_gacc<<<256,256,0,stream>>>(uE,a,x,G,USERN);
    k_gacc<<<256,256,0,stream>>>(iE,a+USERN,x+(size_t)USERN*DD,G+4096,ITEMN);
    k_tm<<<2,256,0,stream>>>(uH,iH,G,Mb);
    k_hyp2<<<256,256,0,stream>>>(uE,a,Mb,hyp,USERN);
    k_hyp2<<<256,256,0,stream>>>(iE,a+USERN,Mb+4096,hyp+(size_t)USERN*DD,ITEMN);
    for(int j=0;j<2;j++){
      float* zb=(j==0)? tem : hyp;
      int ij=i*2+j;
      k_dis<<<512,512,0,stream>>>(zb,
        dW1+(size_t)ij*4*64*64, db1+(size_t)ij*4*64,
        dW2+(size_t)ij*4*64*16, db2+(size_t)ij*4*16,
        dWr1+(size_t)ij*16*64,  dbr1+(size_t)ij*64,
        dWr2+(size_t)ij*64*64,  dbr2+(size_t)ij*64,
        dwts+(size_t)ij*4, dlng+(size_t)ij*64, dlnb+(size_t)ij*64);
    }
    k_gate2<<<512,512,0,stream>>>(tem,hyp,x,out,
      gWg1+(size_t)i*128*64, gbg1+(size_t)i*64,
      gWg2+(size_t)i*64*64,  gbg2+(size_t)i*64,
      gWr1+(size_t)i*128*64, gbr1+(size_t)i*64,
      gWr2+(size_t)i*64*64,  gbr2+(size_t)i*64,
      glng+(size_t)i*64, glnb+(size_t)i*64);
  }
}

// Round 5
// 2863.754 us; speedup vs baseline: 6.6177x; 2.2414x over previous
//
#include <hip/hip_runtime.h>
#include <math.h>

#define USERN 100000
#define ITEMN 200000
#define NND   300000
#define DD    64
#define HH    128
#define FF    16
#define EDG   3000000
#define LEAKY_A 0.5f
#define LN_EPS  1e-5f

typedef __attribute__((ext_vector_type(8))) short bf16x8;
typedef __attribute__((ext_vector_type(4))) float f32x4;
#define MFMA16(a,b,c) __builtin_amdgcn_mfma_f32_16x16x32_bf16(a,b,c,0,0,0)

__device__ __forceinline__ float leaky(float x){ return x>0.f ? x : LEAKY_A*x; }
__device__ __forceinline__ unsigned fenc(float f){ unsigned u=__float_as_uint(f); return (u&0x80000000u)? ~u : (u|0x80000000u); }
__device__ __forceinline__ float fdec(unsigned u){ return (u&0x80000000u)? __uint_as_float(u&0x7fffffffu) : __uint_as_float(~u); }
// f32 -> bf16 bits, round-nearest-even
__device__ __forceinline__ short f2bf(float f){
  unsigned u=__float_as_uint(f);
  unsigned r=u + 0x7fffu + ((u>>16)&1u);
  return (short)(r>>16);
}
// A-frag loader: lane l supplies row (l&15); k-map k = dbase + (l>>4)*4 + (j&3) + 16*(j>>2)
__device__ __forceinline__ bf16x8 loadA(const float* __restrict__ base, int l, int dbase){
  const float* p = base + (size_t)(l&15)*DD + dbase + ((l>>4)<<2);
  float4 a=*(const float4*)p;
  float4 b=*(const float4*)(p+16);
  bf16x8 r;
  r[0]=f2bf(a.x); r[1]=f2bf(a.y); r[2]=f2bf(a.z); r[3]=f2bf(a.w);
  r[4]=f2bf(b.x); r[5]=f2bf(b.y); r[6]=f2bf(b.z); r[7]=f2bf(b.w);
  return r;
}

// ---------------- init: x = concat(uE, iE); out = x ----------------
__global__ __launch_bounds__(256) void k_init(const float* __restrict__ uE, const float* __restrict__ iE,
                        float* __restrict__ x, float* __restrict__ out){
  int tot=NND*DD;
  for(int idx=blockIdx.x*256+threadIdx.x; idx<tot; idx+=gridDim.x*256){
    int n=idx>>6;
    float v=(n<USERN)? uE[idx] : iE[idx-USERN*DD];
    x[idx]=v; out[idx]=v;
  }
}

// ---------------- hv = H @ attn (hv[0:64]=u, hv[64:128]=i) ----------------
__global__ __launch_bounds__(128) void k_hv(const float* __restrict__ uH,const float* __restrict__ iH,
      const float* __restrict__ uA,const float* __restrict__ iA,float* __restrict__ hv){
  int t=threadIdx.x;
  const float* H=(t<64)? uH:iH;
  const float* A=(t<64)? uA:iA;
  int d=t&63;
  float s=0.f;
  for(int h=0;h<HH;h++) s=fmaf(H[d*HH+h],A[h],s);
  hv[t]=s;
}

// ---------------- a[n] = E[n,:] . hv ----------------
__global__ __launch_bounds__(256) void k_att(const float* __restrict__ E, const float* __restrict__ hvp,
      float* __restrict__ a, int U){
  __shared__ float hs[64];
  int tid=threadIdx.x;
  if(tid<64) hs[tid]=hvp[tid];
  __syncthreads();
  int wave=tid>>6, lane=tid&63;
  for(int g=blockIdx.x*4+wave; g<U/4; g+=gridDim.x*4){
    int n0=g*4;
    #pragma unroll
    for(int m=0;m<4;m++){
      float p=E[(size_t)(n0+m)*DD+lane]*hs[lane];
      #pragma unroll
      for(int off=32;off;off>>=1) p+=__shfl_xor(p,off,64);
      if(lane==0) a[n0+m]=p;
    }
  }
}

// ---------------- softmax reductions over node axis ----------------
__global__ __launch_bounds__(256) void k_redmax(const float* __restrict__ a, int n, unsigned* slot){
  float v=-3.0e38f;
  for(int i=blockIdx.x*256+threadIdx.x;i<n;i+=gridDim.x*256) v=fmaxf(v,a[i]);
  #pragma unroll
  for(int off=32;off;off>>=1) v=fmaxf(v,__shfl_xor(v,off,64));
  if((threadIdx.x&63)==0) atomicMax(slot, fenc(v));
}

__global__ __launch_bounds__(256) void k_sumexp(const float* __restrict__ a, int n,
      const unsigned* __restrict__ mslot, float* ssum){
  float mx=fdec(*mslot);
  float s=0.f;
  for(int i=blockIdx.x*256+threadIdx.x;i<n;i+=gridDim.x*256) s+=expf(a[i]-mx);
  #pragma unroll
  for(int off=32;off;off>>=1) s+=__shfl_xor(s,off,64);
  if((threadIdx.x&63)==0) atomicAdd(ssum, s);
}

__global__ __launch_bounds__(256) void k_scale_a(float* __restrict__ a,int n,
      const unsigned* __restrict__ mslot,const float* __restrict__ ssum){
  float mx=fdec(*mslot); float inv=1.f/(*ssum);
  for(int i=blockIdx.x*256+threadIdx.x;i<n;i+=gridDim.x*256) a[i]=expf(a[i]-mx)*inv;
}

// ---------------- SpMM: tem[r,:] += val * x[c,:] (atomic) ----------------
__global__ __launch_bounds__(256) void k_spmm(const float* __restrict__ vals, const int* __restrict__ rows,
      const int* __restrict__ cols, const float* __restrict__ x, float* __restrict__ tem){
  long long tot=(long long)EDG*DD;
  long long stride=(long long)gridDim.x*256;
  for(long long idx=(long long)blockIdx.x*256+threadIdx.x; idx<tot; idx+=stride){
    int e=(int)(idx>>6), d=(int)(idx&63);
    float v=vals[e];
    int r=rows[e], c=cols[e];
    atomicAdd(&tem[(size_t)r*DD+d], v*x[(size_t)c*DD+d]);
  }
}

// ---------------- G[d1,d2] += sum_n s[n]*E[n,d1]*x[n,d2] ----------------
__global__ __launch_bounds__(256) void k_gacc(const float* __restrict__ E,const float* __restrict__ sca,
      const float* __restrict__ x,float* __restrict__ G,int U){
  __shared__ __align__(16) float es[4][256];
  int tid=threadIdx.x, wave=tid>>6, lane=tid&63;
  float acc[64];
  #pragma unroll
  for(int j=0;j<64;j++) acc[j]=0.f;
  float* esw=es[wave];
  for(int g=blockIdx.x*4+wave; g<U/4; g+=gridDim.x*4){
    int n0=g*4;
    float xv[4];
    #pragma unroll
    for(int m=0;m<4;m++){
      float sc=sca[n0+m];
      esw[m*64+lane]=E[(size_t)(n0+m)*DD+lane]*sc;
      xv[m]=x[(size_t)(n0+m)*DD+lane];
    }
    #pragma unroll
    for(int d4=0;d4<16;d4++){
      float4 eb[4];
      #pragma unroll
      for(int m=0;m<4;m++) eb[m]=((const float4*)(esw+m*64))[d4];
      #pragma unroll
      for(int c=0;c<4;c++){
        #pragma unroll
        for(int m=0;m<4;m++) acc[d4*4+c]=fmaf(((const float*)&eb[m])[c],xv[m],acc[d4*4+c]);
      }
    }
  }
  #pragma unroll
  for(int j=0;j<64;j++) atomicAdd(&G[j*64+lane],acc[j]);
}

// ---------------- M = H @ (H^T @ G)  (blockIdx 0=user, 1=item) ----------------
__global__ __launch_bounds__(256) void k_tm(const float* __restrict__ uH,const float* __restrict__ iH,
      const float* __restrict__ G,float* __restrict__ Mo){
  __shared__ __align__(16) float Hs[64*HH];
  __shared__ __align__(16) float Gs[64*64];
  __shared__ __align__(16) float Ts[HH*64];
  const float* H = blockIdx.x ? iH : uH;
  const float* Gp = G + blockIdx.x*4096;
  float* Mp = Mo + blockIdx.x*4096;
  int tid=threadIdx.x;
  for(int k=tid;k<64*HH;k+=256) Hs[k]=H[k];
  for(int k=tid;k<4096;k+=256) Gs[k]=Gp[k];
  __syncthreads();
  int lane=tid&63, wq=tid>>6;
  float tac[32];
  #pragma unroll
  for(int k=0;k<32;k++) tac[k]=0.f;
  for(int d1=0;d1<64;d1++){
    float gv=Gs[d1*64+lane];
    const float4* hrow=(const float4*)(Hs+d1*HH+wq*32);
    #pragma unroll
    for(int k4=0;k4<8;k4++){
      float4 hb=hrow[k4];
      tac[k4*4+0]=fmaf(hb.x,gv,tac[k4*4+0]);
      tac[k4*4+1]=fmaf(hb.y,gv,tac[k4*4+1]);
      tac[k4*4+2]=fmaf(hb.z,gv,tac[k4*4+2]);
      tac[k4*4+3]=fmaf(hb.w,gv,tac[k4*4+3]);
    }
  }
  #pragma unroll
  for(int k=0;k<32;k++) Ts[(wq*32+k)*64+lane]=tac[k];
  __syncthreads();
  float mac[16];
  #pragma unroll
  for(int k=0;k<16;k++) mac[k]=0.f;
  for(int h=0;h<HH;h++){
    float tv=Ts[h*64+lane];
    #pragma unroll
    for(int k=0;k<16;k++) mac[k]=fmaf(Hs[(wq*16+k)*HH+h],tv,mac[k]);
  }
  #pragma unroll
  for(int k=0;k<16;k++) Mp[(wq*16+k)*64+lane]=mac[k];
}

// ---------------- hyp[n,:] = s[n] * E[n,:] @ M ----------------
__global__ __launch_bounds__(256) void k_hyp2(const float* __restrict__ E,const float* __restrict__ sca,
      const float* __restrict__ Mp,float* __restrict__ hyp,int U){
  __shared__ __align__(16) float es[4][256];
  int tid=threadIdx.x, wave=tid>>6, lane=tid&63;
  float mcol[64];
  #pragma unroll
  for(int j=0;j<64;j++) mcol[j]=Mp[j*64+lane];
  float* esw=es[wave];
  for(int g=blockIdx.x*4+wave; g<U/4; g+=gridDim.x*4){
    int n0=g*4;
    #pragma unroll
    for(int m=0;m<4;m++){
      float sc=sca[n0+m];
      esw[m*64+lane]=E[(size_t)(n0+m)*DD+lane]*sc;
    }
    float acc[4]={0,0,0,0};
    #pragma unroll
    for(int d4=0;d4<16;d4++){
      float4 eb[4];
      #pragma unroll
      for(int m=0;m<4;m++) eb[m]=((const float4*)(esw+m*64))[d4];
      #pragma unroll
      for(int c=0;c<4;c++){
        float mv=mcol[d4*4+c];
        #pragma unroll
        for(int m=0;m<4;m++) acc[m]=fmaf(((const float*)&eb[m])[c],mv,acc[m]);
      }
    }
    #pragma unroll
    for(int m=0;m<4;m++) hyp[(size_t)(n0+m)*DD+lane]=acc[m];
  }
}

// ---------------- dis v3: bf16 MFMA 16x16x32, in-place z <- LN(z + rec(z)) ----------------
// B-frag staging bijection identical to k_gate2 (HW-validated): region of 512 bf16 per
// (matrix, kblk, ot); slot s=(c*4+kg)*8+j; k = kb*32 + kg*4 + (j&3) + ((j>>2)<<4).
// Wr1 (K=16) staged into K=32 frame with j>=4 slots zeroed (A garbage x B zero = 0).
// h / rec1 staged per-wave in A-slot layout; comb staged in K=16 A layout (upper pre-zeroed).
__global__ __launch_bounds__(512) void k_dis(
    float* __restrict__ z,
    const float* __restrict__ W1,const float* __restrict__ b1,
    const float* __restrict__ W2,const float* __restrict__ b2,
    const float* __restrict__ Wr1,const float* __restrict__ br1,
    const float* __restrict__ Wr2,const float* __restrict__ br2,
    const float* __restrict__ wsoft,const float* __restrict__ lng,const float* __restrict__ lnb){
  __shared__ __align__(16) short w1s[16384]; // [kk(4)][kb(2)][ot(4)][512]
  __shared__ __align__(16) short w2s[4096];  // [kk(4)][kb(2)][512]
  __shared__ __align__(16) short wr1s[2048]; // [ot(4)][512], j>=4 zero
  __shared__ __align__(16) short wr2s[4096]; // [kb(2)][ot(4)][512]
  __shared__ __align__(16) short hst[8][1024];
  __shared__ __align__(16) short cst[8][512];
  __shared__ float swsh[4];
  int tid=threadIdx.x;
  for(int t=tid;t<16384;t+=512){
    int j=t&7,kg=(t>>3)&3,c=(t>>5)&15,ot=(t>>9)&3,kb=(t>>11)&1,kk=t>>12;
    int k=kb*32+kg*4+(j&3)+((j>>2)<<4), o=ot*16+c;
    w1s[t]=f2bf(W1[(size_t)(kk*64+k)*64+o]);
  }
  for(int t=tid;t<4096;t+=512){
    int j=t&7,kg=(t>>3)&3,c=(t>>5)&15,kb=(t>>9)&1,kk=t>>10;
    int k=kb*32+kg*4+(j&3)+((j>>2)<<4);
    w2s[t]=f2bf(W2[(size_t)(kk*64+k)*16+c]);
  }
  for(int t=tid;t<2048;t+=512){
    int j=t&7,kg=(t>>3)&3,c=(t>>5)&15,ot=t>>9;
    int o=ot*16+c;
    short v=0;
    if(j<4){ int k=kg*4+j; v=f2bf(Wr1[k*64+o]); }
    wr1s[t]=v;
  }
  for(int t=tid;t<4096;t+=512){
    int j=t&7,kg=(t>>3)&3,c=(t>>5)&15,ot=(t>>9)&3,kb=t>>11;
    int k=kb*32+kg*4+(j&3)+((j>>2)<<4), o=ot*16+c;
    wr2s[t]=f2bf(Wr2[k*64+o]);
  }
  if(tid==0){
    float m0=fmaxf(fmaxf(wsoft[0],wsoft[1]),fmaxf(wsoft[2],wsoft[3]));
    float e0=expf(wsoft[0]-m0),e1=expf(wsoft[1]-m0),e2=expf(wsoft[2]-m0),e3=expf(wsoft[3]-m0);
    float s=e0+e1+e2+e3;
    swsh[0]=e0/s; swsh[1]=e1/s; swsh[2]=e2/s; swsh[3]=e3/s;
  }
  __syncthreads();
  int wave=tid>>6, l=tid&63, lr=l&15, lg=l>>4;
  float sw[4]; sw[0]=swsh[0]; sw[1]=swsh[1]; sw[2]=swsh[2]; sw[3]=swsh[3];
  float b1v[4][4], br1v[4], br2v[4], gv[4], bv[4];
  #pragma unroll
  for(int kk=0;kk<4;kk++)
    #pragma unroll
    for(int ot=0;ot<4;ot++) b1v[kk][ot]=b1[kk*64+ot*16+lr];
  float b2c = sw[0]*b2[lr] + sw[1]*b2[16+lr] + sw[2]*b2[32+lr] + sw[3]*b2[48+lr];
  #pragma unroll
  for(int ot=0;ot<4;ot++){
    br1v[ot]=br1[ot*16+lr]; br2v[ot]=br2[ot*16+lr];
    gv[ot]=lng[ot*16+lr];   bv[ot]=lnb[ot*16+lr];
  }
  short* hw=hst[wave];
  short* cw=cst[wave];
  // pre-zero comb buffer's j>=4 slots (never written again; wave-local)
  for(int t=l;t<256;t+=64){
    int r=t>>4, lgp=(t>>2)&3, jj=t&3;
    cw[(r*4+lgp)*8+4+jj]=0;
  }
  int slot=(lr*4+lg)*8;
  const f32x4 zero={0.f,0.f,0.f,0.f};
  for(int tile=blockIdx.x*8+wave; tile<NND/16; tile+=gridDim.x*8){
    int n0=tile*16;
    float* zrow=z+(size_t)n0*DD;
    bf16x8 A0=loadA(zrow,l,0), A1=loadA(zrow,l,32);
    f32x4 cba; cba[0]=b2c; cba[1]=b2c; cba[2]=b2c; cba[3]=b2c;
    #pragma unroll
    for(int kk=0;kk<4;kk++){
      const short* w1k=&w1s[kk*4096];
      // layer1: h = leaky(z @ W1[kk] + b1[kk])  -> stage to hw in A-slot layout
      #pragma unroll
      for(int ot=0;ot<4;ot++){
        f32x4 ha=zero;
        ha=MFMA16(A0,*(const bf16x8*)&w1k[ot*512+slot],ha);
        ha=MFMA16(A1,*(const bf16x8*)&w1k[2048+ot*512+slot],ha);
        int kb2=ot>>1;
        #pragma unroll
        for(int j=0;j<4;j++){
          int addr=kb2*512 + ((lg*4+j)*4 + (lr>>2))*8 + ((ot&1)<<2) + (l&3);
          hw[addr]=f2bf(leaky(ha[j]+b1v[kk][ot]));
        }
      }
      // layer2: f_kk = h @ W2[kk]; comb += sw[kk]*f_kk
      bf16x8 hA0=*(const bf16x8*)&hw[slot];
      bf16x8 hA1=*(const bf16x8*)&hw[512+slot];
      f32x4 fa=zero;
      fa=MFMA16(hA0,*(const bf16x8*)&w2s[kk*1024+slot],fa);
      fa=MFMA16(hA1,*(const bf16x8*)&w2s[kk*1024+512+slot],fa);
      float swk=sw[kk];
      #pragma unroll
      for(int j=0;j<4;j++) cba[j]=fmaf(swk,fa[j],cba[j]);
    }
    // stage comb (K=16) to cw in A-slot layout (j<4 slots)
    #pragma unroll
    for(int j=0;j<4;j++)
      cw[((lg*4+j)*4 + (lr>>2))*8 + (lr&3)] = f2bf(cba[j]);
    // rec1 = leaky(comb @ Wr1 + br1)  (K=16 via zero-padded B)
    bf16x8 cA=*(const bf16x8*)&cw[slot];
    #pragma unroll
    for(int ot=0;ot<4;ot++){
      f32x4 ra=MFMA16(cA,*(const bf16x8*)&wr1s[ot*512+slot],zero);
      int kb2=ot>>1;
      #pragma unroll
      for(int j=0;j<4;j++){
        int addr=kb2*512 + ((lg*4+j)*4 + (lr>>2))*8 + ((ot&1)<<2) + (l&3);
        hw[addr]=f2bf(leaky(ra[j]+br1v[ot]));
      }
    }
    // rec = rec1 @ Wr2 + br2 ; y = z + rec ; LN
    bf16x8 rA0=*(const bf16x8*)&hw[slot];
    bf16x8 rA1=*(const bf16x8*)&hw[512+slot];
    float y[4][4];
    #pragma unroll
    for(int ot=0;ot<4;ot++){
      f32x4 rc=zero;
      rc=MFMA16(rA0,*(const bf16x8*)&wr2s[ot*512+slot],rc);
      rc=MFMA16(rA1,*(const bf16x8*)&wr2s[2048+ot*512+slot],rc);
      #pragma unroll
      for(int j=0;j<4;j++){
        float zd=zrow[(size_t)(lg*4+j)*DD + ot*16+lr];
        y[ot][j]=zd + rc[j] + br2v[ot];
      }
    }
    #pragma unroll
    for(int j=0;j<4;j++){
      float s=y[0][j]+y[1][j]+y[2][j]+y[3][j];
      s+=__shfl_xor(s,1,64); s+=__shfl_xor(s,2,64); s+=__shfl_xor(s,4,64); s+=__shfl_xor(s,8,64);
      float mean=s*(1.f/64.f);
      float t0=y[0][j]-mean, t1=y[1][j]-mean, t2=y[2][j]-mean, t3=y[3][j]-mean;
      float s2=t0*t0+t1*t1+t2*t2+t3*t3;
      s2+=__shfl_xor(s2,1,64); s2+=__shfl_xor(s2,2,64); s2+=__shfl_xor(s2,4,64); s2+=__shfl_xor(s2,8,64);
      float inv=rsqrtf(s2*(1.f/64.f)+LN_EPS);
      zrow[(size_t)(lg*4+j)*DD +  0+lr]=t0*inv*gv[0]+bv[0];
      zrow[(size_t)(lg*4+j)*DD + 16+lr]=t1*inv*gv[1]+bv[1];
      zrow[(size_t)(lg*4+j)*DD + 32+lr]=t2*inv*gv[2]+bv[2];
      zrow[(size_t)(lg*4+j)*DD + 48+lr]=t3*inv*gv[3]+bv[3];
    }
  }
}

// ---------------- gate2 v3: bf16 MFMA 16x16x32, 16 nodes/wave (unchanged) ----------------
__global__ __launch_bounds__(512) void k_gate2(
    const float* __restrict__ tem, const float* __restrict__ hyp,
    float* __restrict__ x, float* __restrict__ out,
    const float* __restrict__ Wg1,const float* __restrict__ bg1,
    const float* __restrict__ Wg2,const float* __restrict__ bg2,
    const float* __restrict__ Wr1,const float* __restrict__ br1,
    const float* __restrict__ Wr2,const float* __restrict__ br2,
    const float* __restrict__ lng,const float* __restrict__ lnb){
  __shared__ __align__(16) short g1s[4*4*512];
  __shared__ __align__(16) short r1s[4*4*512];
  __shared__ __align__(16) short g2s[2*4*512];
  __shared__ __align__(16) short r2s[2*4*512];
  __shared__ __align__(16) short hls[8][2][1024];
  int tid=threadIdx.x;
  for(int t=tid;t<8192;t+=512){
    int j=t&7,kg=(t>>3)&3,c=(t>>5)&15,ot=(t>>9)&3,kb=t>>11;
    int k=kb*32+kg*4+(j&3)+((j>>2)<<4), o=ot*16+c;
    g1s[t]=f2bf(Wg1[k*64+o]);
    r1s[t]=f2bf(Wr1[k*64+o]);
  }
  for(int t=tid;t<4096;t+=512){
    int j=t&7,kg=(t>>3)&3,c=(t>>5)&15,ot=(t>>9)&3,kb=t>>11;
    int k=kb*32+kg*4+(j&3)+((j>>2)<<4), o=ot*16+c;
    g2s[t]=f2bf(Wg2[k*64+o]);
    r2s[t]=f2bf(Wr2[k*64+o]);
  }
  __syncthreads();
  int wave=tid>>6, l=tid&63;
  int lr=l&15, lg=l>>4;
  float bg1v[4],br1v[4],bg2v[4],br2v[4],gv[4],bv[4];
  #pragma unroll
  for(int ot=0;ot<4;ot++){
    bg1v[ot]=bg1[ot*16+lr]; br1v[ot]=br1[ot*16+lr];
    bg2v[ot]=bg2[ot*16+lr]; br2v[ot]=br2[ot*16+lr];
    gv[ot]=lng[ot*16+lr];   bv[ot]=lnb[ot*16+lr];
  }
  short* hG=&hls[wave][0][0];
  short* hR=&hls[wave][1][0];
  int slot=(lr*4+lg)*8;
  const f32x4 zero={0.f,0.f,0.f,0.f};
  for(int tile=blockIdx.x*8+wave; tile<NND/16; tile+=gridDim.x*8){
    int n0=tile*16;
    const float* xrow=x+(size_t)n0*DD;
    bf16x8 pA0=loadA(xrow,l,0), pA1=loadA(xrow,l,32);
    f32x4 pg[4],pr[4];
    #pragma unroll
    for(int ot=0;ot<4;ot++){
      f32x4 ag=zero, ar=zero;
      ag=MFMA16(pA0,*(const bf16x8*)&g1s[(2*4+ot)*512+slot],ag);
      ag=MFMA16(pA1,*(const bf16x8*)&g1s[(3*4+ot)*512+slot],ag);
      ar=MFMA16(pA0,*(const bf16x8*)&r1s[(2*4+ot)*512+slot],ar);
      ar=MFMA16(pA1,*(const bf16x8*)&r1s[(3*4+ot)*512+slot],ar);
      pg[ot]=ag; pr[ot]=ar;
    }
    float ya[4][4];
    #pragma unroll
    for(int p=0;p<2;p++){
      const float* cur=(p? hyp : tem)+(size_t)n0*DD;
      bf16x8 cA0=loadA(cur,l,0), cA1=loadA(cur,l,32);
      #pragma unroll
      for(int ot=0;ot<4;ot++){
        f32x4 ag=pg[ot], ar=pr[ot];
        ag=MFMA16(cA0,*(const bf16x8*)&g1s[(0*4+ot)*512+slot],ag);
        ag=MFMA16(cA1,*(const bf16x8*)&g1s[(1*4+ot)*512+slot],ag);
        ar=MFMA16(cA0,*(const bf16x8*)&r1s[(0*4+ot)*512+slot],ar);
        ar=MFMA16(cA1,*(const bf16x8*)&r1s[(1*4+ot)*512+slot],ar);
        int kb2=ot>>1;
        #pragma unroll
        for(int j=0;j<4;j++){
          int addr=kb2*512 + ((lg*4+j)*4 + (lr>>2))*8 + ((ot&1)<<2) + (l&3);
          hG[addr]=f2bf(fmaxf(ag[j]+bg1v[ot],0.f));
          hR[addr]=f2bf(leaky(ar[j]+br1v[ot]));
        }
      }
      bf16x8 hgA0=*(const bf16x8*)&hG[slot],    hgA1=*(const bf16x8*)&hG[512+slot];
      bf16x8 hrA0=*(const bf16x8*)&hR[slot],    hrA1=*(const bf16x8*)&hR[512+slot];
      f32x4 g2a[4], r2a[4];
      #pragma unroll
      for(int ot=0;ot<4;ot++){
        f32x4 ag=zero, ar=zero;
        ag=MFMA16(hgA0,*(const bf16x8*)&g2s[(0*4+ot)*512+slot],ag);
        ag=MFMA16(hgA1,*(const bf16x8*)&g2s[(1*4+ot)*512+slot],ag);
        ar=MFMA16(hrA0,*(const bf16x8*)&r2s[(0*4+ot)*512+slot],ar);
        ar=MFMA16(hrA1,*(const bf16x8*)&r2s[(1*4+ot)*512+slot],ar);
        g2a[ot]=ag; r2a[ot]=ar;
      }
      float y[4][4];
      #pragma unroll
      for(int ot=0;ot<4;ot++){
        #pragma unroll
        for(int j=0;j<4;j++){
          float cd=cur[(size_t)(lg*4+j)*DD + ot*16+lr];
          float gw=1.f/(1.f+expf(-(g2a[ot][j]+bg2v[ot])));
          y[ot][j]=gw*(r2a[ot][j]+br2v[ot])+cd;
        }
      }
      #pragma unroll
      for(int j=0;j<4;j++){
        float s=y[0][j]+y[1][j]+y[2][j]+y[3][j];
        s+=__shfl_xor(s,1,64); s+=__shfl_xor(s,2,64); s+=__shfl_xor(s,4,64); s+=__shfl_xor(s,8,64);
        float mean=s*(1.f/64.f);
        float t0=y[0][j]-mean, t1=y[1][j]-mean, t2=y[2][j]-mean, t3=y[3][j]-mean;
        float s2=t0*t0+t1*t1+t2*t2+t3*t3;
        s2+=__shfl_xor(s2,1,64); s2+=__shfl_xor(s2,2,64); s2+=__shfl_xor(s2,4,64); s2+=__shfl_xor(s2,8,64);
        float inv=rsqrtf(s2*(1.f/64.f)+LN_EPS);
        float yn0=t0*inv*gv[0]+bv[0];
        float yn1=t1*inv*gv[1]+bv[1];
        float yn2=t2*inv*gv[2]+bv[2];
        float yn3=t3*inv*gv[3]+bv[3];
        if(p==0){ ya[0][j]=yn0; ya[1][j]=yn1; ya[2][j]=yn2; ya[3][j]=yn3; }
        else    { ya[0][j]+=yn0; ya[1][j]+=yn1; ya[2][j]+=yn2; ya[3][j]+=yn3; }
      }
    }
    #pragma unroll
    for(int ot=0;ot<4;ot++){
      #pragma unroll
      for(int j=0;j<4;j++){
        size_t idx=(size_t)(n0+lg*4+j)*DD + ot*16+lr;
        x[idx]=ya[ot][j];
        out[idx]+=ya[ot][j];
      }
    }
  }
}

extern "C" void kernel_launch(void* const* d_in, const int* in_sizes, int n_in,
                              void* d_out, int out_size, void* d_ws, size_t ws_size,
                              hipStream_t stream){
  const float* uE  =(const float*)d_in[0];
  const float* iE  =(const float*)d_in[1];
  const float* uH  =(const float*)d_in[2];
  const float* iH  =(const float*)d_in[3];
  const float* uA  =(const float*)d_in[4];
  const float* iA  =(const float*)d_in[5];
  const float* dW1 =(const float*)d_in[6];
  const float* db1 =(const float*)d_in[7];
  const float* dW2 =(const float*)d_in[8];
  const float* db2 =(const float*)d_in[9];
  const float* dWr1=(const float*)d_in[10];
  const float* dbr1=(const float*)d_in[11];
  const float* dWr2=(const float*)d_in[12];
  const float* dbr2=(const float*)d_in[13];
  const float* dwts=(const float*)d_in[14];
  const float* dlng=(const float*)d_in[15];
  const float* dlnb=(const float*)d_in[16];
  const float* gWg1=(const float*)d_in[17];
  const float* gbg1=(const float*)d_in[18];
  const float* gWg2=(const float*)d_in[19];
  const float* gbg2=(const float*)d_in[20];
  const float* gWr1=(const float*)d_in[21];
  const float* gbr1=(const float*)d_in[22];
  const float* gWr2=(const float*)d_in[23];
  const float* gbr2=(const float*)d_in[24];
  const float* glng=(const float*)d_in[25];
  const float* glnb=(const float*)d_in[26];
  const float* avals=(const float*)d_in[27];
  const int*   arows=(const int*)d_in[28];
  const int*   acols=(const int*)d_in[29];
  float* out=(float*)d_out;
  float* ws =(float*)d_ws;

  size_t need = ((size_t)3*NND*DD + NND + 128 + 8192 + 8192 + 8)*sizeof(float);
  if(ws_size < need) return;

  float* x   = ws;
  float* tem = x   + (size_t)NND*DD;
  float* hyp = tem + (size_t)NND*DD;
  float* a   = hyp + (size_t)NND*DD;
  float* hv  = a   + NND;
  float* G   = hv  + 128;
  float* Mb  = G   + 8192;
  float* red = Mb  + 8192;

  hipMemsetAsync(red, 0, 8*sizeof(float), stream);
  k_init<<<2048,256,0,stream>>>(uE,iE,x,out);
  k_hv<<<1,128,0,stream>>>(uH,iH,uA,iA,hv);
  k_att<<<256,256,0,stream>>>(uE,hv,a,USERN);
  k_att<<<256,256,0,stream>>>(iE,hv+64,a+USERN,ITEMN);
  k_redmax<<<256,256,0,stream>>>(a,USERN,(unsigned*)red);
  k_redmax<<<256,256,0,stream>>>(a+USERN,ITEMN,(unsigned*)red+2);
  k_sumexp<<<256,256,0,stream>>>(a,USERN,(const unsigned*)red,red+1);
  k_sumexp<<<256,256,0,stream>>>(a+USERN,ITEMN,(const unsigned*)red+2,red+3);
  k_scale_a<<<256,256,0,stream>>>(a,USERN,(const unsigned*)red,red+1);
  k_scale_a<<<256,256,0,stream>>>(a+USERN,ITEMN,(const unsigned*)red+2,red+3);

  for(int i=0;i<2;i++){
    hipMemsetAsync(tem,0,(size_t)NND*DD*sizeof(float),stream);
    k_spmm<<<8192,256,0,stream>>>(avals,arows,acols,x,tem);
    hipMemsetAsync(G,0,8192*sizeof(float),stream);
    k_gacc<<<256,256,0,stream>>>(uE,a,x,G,USERN);
    k_gacc<<<256,256,0,stream>>>(iE,a+USERN,x+(size_t)USERN*DD,G+4096,ITEMN);
    k_tm<<<2,256,0,stream>>>(uH,iH,G,Mb);
    k_hyp2<<<256,256,0,stream>>>(uE,a,Mb,hyp,USERN);
    k_hyp2<<<256,256,0,stream>>>(iE,a+USERN,Mb+4096,hyp+(size_t)USERN*DD,ITEMN);
    for(int j=0;j<2;j++){
      float* zb=(j==0)? tem : hyp;
      int ij=i*2+j;
      k_dis<<<512,512,0,stream>>>(zb,
        dW1+(size_t)ij*4*64*64, db1+(size_t)ij*4*64,
        dW2+(size_t)ij*4*64*16, db2+(size_t)ij*4*16,
        dWr1+(size_t)ij*16*64,  dbr1+(size_t)ij*64,
        dWr2+(size_t)ij*64*64,  dbr2+(size_t)ij*64,
        dwts+(size_t)ij*4, dlng+(size_t)ij*64, dlnb+(size_t)ij*64);
    }
    k_gate2<<<512,512,0,stream>>>(tem,hyp,x,out,
      gWg1+(size_t)i*128*64, gbg1+(size_t)i*64,
      gWg2+(size_t)i*64*64,  gbg2+(size_t)i*64,
      gWr1+(size_t)i*128*64, gbr1+(size_t)i*64,
      gWr2+(size_t)i*64*64,  gbr2+(size_t)i*64,
      glng+(size_t)i*64, glnb+(size_t)i*64);
  }
}

// Round 6
// 2652.607 us; speedup vs baseline: 7.1445x; 1.0796x over previous
//
#include <hip/hip_runtime.h>
#include <math.h>

#define USERN 100000
#define ITEMN 200000
#define NND   300000
#define DD    64
#define HH    128
#define FF    16
#define EDG   3000000
#define LEAKY_A 0.5f
#define LN_EPS  1e-5f
#define SCHUNK 1024
#define SNB ((NND+SCHUNK-1)/SCHUNK)

typedef __attribute__((ext_vector_type(8))) short bf16x8;
typedef __attribute__((ext_vector_type(4))) float f32x4;
#define MFMA16(a,b,c) __builtin_amdgcn_mfma_f32_16x16x32_bf16(a,b,c,0,0,0)

__device__ __forceinline__ float leaky(float x){ return x>0.f ? x : LEAKY_A*x; }
__device__ __forceinline__ unsigned fenc(float f){ unsigned u=__float_as_uint(f); return (u&0x80000000u)? ~u : (u|0x80000000u); }
__device__ __forceinline__ float fdec(unsigned u){ return (u&0x80000000u)? __uint_as_float(u&0x7fffffffu) : __uint_as_float(~u); }
__device__ __forceinline__ short f2bf(float f){
  unsigned u=__float_as_uint(f);
  unsigned r=u + 0x7fffu + ((u>>16)&1u);
  return (short)(r>>16);
}
__device__ __forceinline__ bf16x8 loadA(const float* __restrict__ base, int l, int dbase){
  const float* p = base + (size_t)(l&15)*DD + dbase + ((l>>4)<<2);
  float4 a=*(const float4*)p;
  float4 b=*(const float4*)(p+16);
  bf16x8 r;
  r[0]=f2bf(a.x); r[1]=f2bf(a.y); r[2]=f2bf(a.z); r[3]=f2bf(a.w);
  r[4]=f2bf(b.x); r[5]=f2bf(b.y); r[6]=f2bf(b.z); r[7]=f2bf(b.w);
  return r;
}

// ---------------- init: x = concat(uE, iE); out = x ----------------
__global__ __launch_bounds__(256) void k_init(const float* __restrict__ uE, const float* __restrict__ iE,
                        float* __restrict__ x, float* __restrict__ out){
  int tot=NND*DD;
  for(int idx=blockIdx.x*256+threadIdx.x; idx<tot; idx+=gridDim.x*256){
    int n=idx>>6;
    float v=(n<USERN)? uE[idx] : iE[idx-USERN*DD];
    x[idx]=v; out[idx]=v;
  }
}

// ---------------- hv = H @ attn (hv[0:64]=u, hv[64:128]=i) ----------------
__global__ __launch_bounds__(128) void k_hv(const float* __restrict__ uH,const float* __restrict__ iH,
      const float* __restrict__ uA,const float* __restrict__ iA,float* __restrict__ hv){
  int t=threadIdx.x;
  const float* H=(t<64)? uH:iH;
  const float* A=(t<64)? uA:iA;
  int d=t&63;
  float s=0.f;
  for(int h=0;h<HH;h++) s=fmaf(H[d*HH+h],A[h],s);
  hv[t]=s;
}

// ---------------- a[n] = E[n,:] . hv ----------------
__global__ __launch_bounds__(256) void k_att(const float* __restrict__ E, const float* __restrict__ hvp,
      float* __restrict__ a, int U){
  __shared__ float hs[64];
  int tid=threadIdx.x;
  if(tid<64) hs[tid]=hvp[tid];
  __syncthreads();
  int wave=tid>>6, lane=tid&63;
  for(int g=blockIdx.x*4+wave; g<U/4; g+=gridDim.x*4){
    int n0=g*4;
    #pragma unroll
    for(int m=0;m<4;m++){
      float p=E[(size_t)(n0+m)*DD+lane]*hs[lane];
      #pragma unroll
      for(int off=32;off;off>>=1) p+=__shfl_xor(p,off,64);
      if(lane==0) a[n0+m]=p;
    }
  }
}

// ---------------- softmax reductions over node axis ----------------
__global__ __launch_bounds__(256) void k_redmax(const float* __restrict__ a, int n, unsigned* slot){
  float v=-3.0e38f;
  for(int i=blockIdx.x*256+threadIdx.x;i<n;i+=gridDim.x*256) v=fmaxf(v,a[i]);
  #pragma unroll
  for(int off=32;off;off>>=1) v=fmaxf(v,__shfl_xor(v,off,64));
  if((threadIdx.x&63)==0) atomicMax(slot, fenc(v));
}

__global__ __launch_bounds__(256) void k_sumexp(const float* __restrict__ a, int n,
      const unsigned* __restrict__ mslot, float* ssum){
  float mx=fdec(*mslot);
  float s=0.f;
  for(int i=blockIdx.x*256+threadIdx.x;i<n;i+=gridDim.x*256) s+=expf(a[i]-mx);
  #pragma unroll
  for(int off=32;off;off>>=1) s+=__shfl_xor(s,off,64);
  if((threadIdx.x&63)==0) atomicAdd(ssum, s);
}

__global__ __launch_bounds__(256) void k_scale_a(float* __restrict__ a,int n,
      const unsigned* __restrict__ mslot,const float* __restrict__ ssum){
  float mx=fdec(*mslot); float inv=1.f/(*ssum);
  for(int i=blockIdx.x*256+threadIdx.x;i<n;i+=gridDim.x*256) a[i]=expf(a[i]-mx)*inv;
}

// ---------------- CSR build: histogram -> scan -> scatter ----------------
__global__ __launch_bounds__(256) void k_hist(const int* __restrict__ rows, int* __restrict__ cnt){
  for(int e=blockIdx.x*256+threadIdx.x; e<EDG; e+=gridDim.x*256)
    atomicAdd(&cnt[rows[e]],1);
}

__global__ __launch_bounds__(256) void k_scanA(int* __restrict__ cnt, int* __restrict__ bsum){
  __shared__ int part[256];
  int b=blockIdx.x, t=threadIdx.x;
  int base=b*SCHUNK;
  int v[4]; int s=0;
  #pragma unroll
  for(int k2=0;k2<4;k2++){
    int idx=base+t*4+k2;
    int val=(idx<NND)? cnt[idx]:0;
    v[k2]=s; s+=val;
  }
  part[t]=s;
  __syncthreads();
  for(int off=1;off<256;off<<=1){
    int y=(t>=off)? part[t-off]:0;
    __syncthreads();
    part[t]+=y;
    __syncthreads();
  }
  int excl=(t==0)?0:part[t-1];
  #pragma unroll
  for(int k2=0;k2<4;k2++){
    int idx=base+t*4+k2;
    if(idx<NND) cnt[idx]=excl+v[k2];
  }
  if(t==255) bsum[b]=part[255];
}

__global__ __launch_bounds__(512) void k_scanB(int* __restrict__ bsum){
  __shared__ int part[512];
  int t=threadIdx.x;
  part[t]=(t<SNB)? bsum[t]:0;
  __syncthreads();
  for(int off=1;off<512;off<<=1){
    int y=(t>=off)? part[t-off]:0;
    __syncthreads();
    part[t]+=y;
    __syncthreads();
  }
  if(t<SNB) bsum[t]=(t==0)?0:part[t-1];
}

__global__ __launch_bounds__(256) void k_scanC(int* __restrict__ rowptr, const int* __restrict__ bsum,
      int* __restrict__ wcur){
  for(int i=blockIdx.x*256+threadIdx.x; i<NND; i+=gridDim.x*256){
    int v=rowptr[i]+bsum[i>>10];
    rowptr[i]=v; wcur[i]=v;
  }
  if(blockIdx.x==0 && threadIdx.x==0) rowptr[NND]=EDG;
}

__global__ __launch_bounds__(256) void k_scatter(const int* __restrict__ rows,const int* __restrict__ cols,
      const float* __restrict__ vals, int* __restrict__ wcur,
      int* __restrict__ ecol, float* __restrict__ eval){
  for(int e=blockIdx.x*256+threadIdx.x; e<EDG; e+=gridDim.x*256){
    int r=rows[e];
    int pos=atomicAdd(&wcur[r],1);
    ecol[pos]=cols[e];
    eval[pos]=vals[e];
  }
}

// ---------------- CSR SpMM: wave per row, no atomics ----------------
__global__ __launch_bounds__(512) void k_spmm_csr(const int* __restrict__ rowptr,
      const int* __restrict__ ecol, const float* __restrict__ eval,
      const float* __restrict__ x, float* __restrict__ tem){
  int wave=threadIdx.x>>6, lane=threadIdx.x&63;
  for(int r=blockIdx.x*8+wave; r<NND; r+=gridDim.x*8){
    int st=rowptr[r], en=rowptr[r+1];
    float acc=0.f;
    int p=st;
    for(; p+1<en; p+=2){
      int c0=ecol[p], c1=ecol[p+1];
      float v0=eval[p], v1=eval[p+1];
      float x0=x[(size_t)c0*DD+lane];
      float x1=x[(size_t)c1*DD+lane];
      acc=fmaf(v0,x0,acc);
      acc=fmaf(v1,x1,acc);
    }
    if(p<en) acc=fmaf(eval[p], x[(size_t)ecol[p]*DD+lane], acc);
    tem[(size_t)r*DD+lane]=acc;
  }
}

// ---------------- G[d1,d2] += sum_n s[n]*E[n,d1]*x[n,d2] ----------------
__global__ __launch_bounds__(256) void k_gacc(const float* __restrict__ E,const float* __restrict__ sca,
      const float* __restrict__ x,float* __restrict__ G,int U){
  __shared__ __align__(16) float es[4][256];
  int tid=threadIdx.x, wave=tid>>6, lane=tid&63;
  float acc[64];
  #pragma unroll
  for(int j=0;j<64;j++) acc[j]=0.f;
  float* esw=es[wave];
  for(int g=blockIdx.x*4+wave; g<U/4; g+=gridDim.x*4){
    int n0=g*4;
    float xv[4];
    #pragma unroll
    for(int m=0;m<4;m++){
      float sc=sca[n0+m];
      esw[m*64+lane]=E[(size_t)(n0+m)*DD+lane]*sc;
      xv[m]=x[(size_t)(n0+m)*DD+lane];
    }
    #pragma unroll
    for(int d4=0;d4<16;d4++){
      float4 eb[4];
      #pragma unroll
      for(int m=0;m<4;m++) eb[m]=((const float4*)(esw+m*64))[d4];
      #pragma unroll
      for(int c=0;c<4;c++){
        #pragma unroll
        for(int m=0;m<4;m++) acc[d4*4+c]=fmaf(((const float*)&eb[m])[c],xv[m],acc[d4*4+c]);
      }
    }
  }
  #pragma unroll
  for(int j=0;j<64;j++) atomicAdd(&G[j*64+lane],acc[j]);
}

// ---------------- M = H @ (H^T @ G)  (blockIdx 0=user, 1=item) ----------------
__global__ __launch_bounds__(256) void k_tm(const float* __restrict__ uH,const float* __restrict__ iH,
      const float* __restrict__ G,float* __restrict__ Mo){
  __shared__ __align__(16) float Hs[64*HH];
  __shared__ __align__(16) float Gs[64*64];
  __shared__ __align__(16) float Ts[HH*64];
  const float* H = blockIdx.x ? iH : uH;
  const float* Gp = G + blockIdx.x*4096;
  float* Mp = Mo + blockIdx.x*4096;
  int tid=threadIdx.x;
  for(int k=tid;k<64*HH;k+=256) Hs[k]=H[k];
  for(int k=tid;k<4096;k+=256) Gs[k]=Gp[k];
  __syncthreads();
  int lane=tid&63, wq=tid>>6;
  float tac[32];
  #pragma unroll
  for(int k=0;k<32;k++) tac[k]=0.f;
  for(int d1=0;d1<64;d1++){
    float gv=Gs[d1*64+lane];
    const float4* hrow=(const float4*)(Hs+d1*HH+wq*32);
    #pragma unroll
    for(int k4=0;k4<8;k4++){
      float4 hb=hrow[k4];
      tac[k4*4+0]=fmaf(hb.x,gv,tac[k4*4+0]);
      tac[k4*4+1]=fmaf(hb.y,gv,tac[k4*4+1]);
      tac[k4*4+2]=fmaf(hb.z,gv,tac[k4*4+2]);
      tac[k4*4+3]=fmaf(hb.w,gv,tac[k4*4+3]);
    }
  }
  #pragma unroll
  for(int k=0;k<32;k++) Ts[(wq*32+k)*64+lane]=tac[k];
  __syncthreads();
  float mac[16];
  #pragma unroll
  for(int k=0;k<16;k++) mac[k]=0.f;
  for(int h=0;h<HH;h++){
    float tv=Ts[h*64+lane];
    #pragma unroll
    for(int k=0;k<16;k++) mac[k]=fmaf(Hs[(wq*16+k)*HH+h],tv,mac[k]);
  }
  #pragma unroll
  for(int k=0;k<16;k++) Mp[(wq*16+k)*64+lane]=mac[k];
}

// ---------------- hyp[n,:] = s[n] * E[n,:] @ M ----------------
__global__ __launch_bounds__(256) void k_hyp2(const float* __restrict__ E,const float* __restrict__ sca,
      const float* __restrict__ Mp,float* __restrict__ hyp,int U){
  __shared__ __align__(16) float es[4][256];
  int tid=threadIdx.x, wave=tid>>6, lane=tid&63;
  float mcol[64];
  #pragma unroll
  for(int j=0;j<64;j++) mcol[j]=Mp[j*64+lane];
  float* esw=es[wave];
  for(int g=blockIdx.x*4+wave; g<U/4; g+=gridDim.x*4){
    int n0=g*4;
    #pragma unroll
    for(int m=0;m<4;m++){
      float sc=sca[n0+m];
      esw[m*64+lane]=E[(size_t)(n0+m)*DD+lane]*sc;
    }
    float acc[4]={0,0,0,0};
    #pragma unroll
    for(int d4=0;d4<16;d4++){
      float4 eb[4];
      #pragma unroll
      for(int m=0;m<4;m++) eb[m]=((const float4*)(esw+m*64))[d4];
      #pragma unroll
      for(int c=0;c<4;c++){
        float mv=mcol[d4*4+c];
        #pragma unroll
        for(int m=0;m<4;m++) acc[m]=fmaf(((const float*)&eb[m])[c],mv,acc[m]);
      }
    }
    #pragma unroll
    for(int m=0;m<4;m++) hyp[(size_t)(n0+m)*DD+lane]=acc[m];
  }
}

// ---------------- dis v3: bf16 MFMA 16x16x32 (unchanged) ----------------
__global__ __launch_bounds__(512) void k_dis(
    float* __restrict__ z,
    const float* __restrict__ W1,const float* __restrict__ b1,
    const float* __restrict__ W2,const float* __restrict__ b2,
    const float* __restrict__ Wr1,const float* __restrict__ br1,
    const float* __restrict__ Wr2,const float* __restrict__ br2,
    const float* __restrict__ wsoft,const float* __restrict__ lng,const float* __restrict__ lnb){
  __shared__ __align__(16) short w1s[16384];
  __shared__ __align__(16) short w2s[4096];
  __shared__ __align__(16) short wr1s[2048];
  __shared__ __align__(16) short wr2s[4096];
  __shared__ __align__(16) short hst[8][1024];
  __shared__ __align__(16) short cst[8][512];
  __shared__ float swsh[4];
  int tid=threadIdx.x;
  for(int t=tid;t<16384;t+=512){
    int j=t&7,kg=(t>>3)&3,c=(t>>5)&15,ot=(t>>9)&3,kb=(t>>11)&1,kk=t>>12;
    int k=kb*32+kg*4+(j&3)+((j>>2)<<4), o=ot*16+c;
    w1s[t]=f2bf(W1[(size_t)(kk*64+k)*64+o]);
  }
  for(int t=tid;t<4096;t+=512){
    int j=t&7,kg=(t>>3)&3,c=(t>>5)&15,kb=(t>>9)&1,kk=t>>10;
    int k=kb*32+kg*4+(j&3)+((j>>2)<<4);
    w2s[t]=f2bf(W2[(size_t)(kk*64+k)*16+c]);
  }
  for(int t=tid;t<2048;t+=512){
    int j=t&7,kg=(t>>3)&3,c=(t>>5)&15,ot=t>>9;
    int o=ot*16+c;
    short v=0;
    if(j<4){ int k=kg*4+j; v=f2bf(Wr1[k*64+o]); }
    wr1s[t]=v;
  }
  for(int t=tid;t<4096;t+=512){
    int j=t&7,kg=(t>>3)&3,c=(t>>5)&15,ot=(t>>9)&3,kb=t>>11;
    int k=kb*32+kg*4+(j&3)+((j>>2)<<4), o=ot*16+c;
    wr2s[t]=f2bf(Wr2[k*64+o]);
  }
  if(tid==0){
    float m0=fmaxf(fmaxf(wsoft[0],wsoft[1]),fmaxf(wsoft[2],wsoft[3]));
    float e0=expf(wsoft[0]-m0),e1=expf(wsoft[1]-m0),e2=expf(wsoft[2]-m0),e3=expf(wsoft[3]-m0);
    float s=e0+e1+e2+e3;
    swsh[0]=e0/s; swsh[1]=e1/s; swsh[2]=e2/s; swsh[3]=e3/s;
  }
  __syncthreads();
  int wave=tid>>6, l=tid&63, lr=l&15, lg=l>>4;
  float sw[4]; sw[0]=swsh[0]; sw[1]=swsh[1]; sw[2]=swsh[2]; sw[3]=swsh[3];
  float b1v[4][4], br1v[4], br2v[4], gv[4], bv[4];
  #pragma unroll
  for(int kk=0;kk<4;kk++)
    #pragma unroll
    for(int ot=0;ot<4;ot++) b1v[kk][ot]=b1[kk*64+ot*16+lr];
  float b2c = sw[0]*b2[lr] + sw[1]*b2[16+lr] + sw[2]*b2[32+lr] + sw[3]*b2[48+lr];
  #pragma unroll
  for(int ot=0;ot<4;ot++){
    br1v[ot]=br1[ot*16+lr]; br2v[ot]=br2[ot*16+lr];
    gv[ot]=lng[ot*16+lr];   bv[ot]=lnb[ot*16+lr];
  }
  short* hw=hst[wave];
  short* cw=cst[wave];
  for(int t=l;t<256;t+=64){
    int r=t>>4, lgp=(t>>2)&3, jj=t&3;
    cw[(r*4+lgp)*8+4+jj]=0;
  }
  int slot=(lr*4+lg)*8;
  const f32x4 zero={0.f,0.f,0.f,0.f};
  for(int tile=blockIdx.x*8+wave; tile<NND/16; tile+=gridDim.x*8){
    int n0=tile*16;
    float* zrow=z+(size_t)n0*DD;
    bf16x8 A0=loadA(zrow,l,0), A1=loadA(zrow,l,32);
    f32x4 cba; cba[0]=b2c; cba[1]=b2c; cba[2]=b2c; cba[3]=b2c;
    #pragma unroll
    for(int kk=0;kk<4;kk++){
      const short* w1k=&w1s[kk*4096];
      #pragma unroll
      for(int ot=0;ot<4;ot++){
        f32x4 ha=zero;
        ha=MFMA16(A0,*(const bf16x8*)&w1k[ot*512+slot],ha);
        ha=MFMA16(A1,*(const bf16x8*)&w1k[2048+ot*512+slot],ha);
        int kb2=ot>>1;
        #pragma unroll
        for(int j=0;j<4;j++){
          int addr=kb2*512 + ((lg*4+j)*4 + (lr>>2))*8 + ((ot&1)<<2) + (l&3);
          hw[addr]=f2bf(leaky(ha[j]+b1v[kk][ot]));
        }
      }
      bf16x8 hA0=*(const bf16x8*)&hw[slot];
      bf16x8 hA1=*(const bf16x8*)&hw[512+slot];
      f32x4 fa=zero;
      fa=MFMA16(hA0,*(const bf16x8*)&w2s[kk*1024+slot],fa);
      fa=MFMA16(hA1,*(const bf16x8*)&w2s[kk*1024+512+slot],fa);
      float swk=sw[kk];
      #pragma unroll
      for(int j=0;j<4;j++) cba[j]=fmaf(swk,fa[j],cba[j]);
    }
    #pragma unroll
    for(int j=0;j<4;j++)
      cw[((lg*4+j)*4 + (lr>>2))*8 + (lr&3)] = f2bf(cba[j]);
    bf16x8 cA=*(const bf16x8*)&cw[slot];
    #pragma unroll
    for(int ot=0;ot<4;ot++){
      f32x4 ra=MFMA16(cA,*(const bf16x8*)&wr1s[ot*512+slot],zero);
      int kb2=ot>>1;
      #pragma unroll
      for(int j=0;j<4;j++){
        int addr=kb2*512 + ((lg*4+j)*4 + (lr>>2))*8 + ((ot&1)<<2) + (l&3);
        hw[addr]=f2bf(leaky(ra[j]+br1v[ot]));
      }
    }
    bf16x8 rA0=*(const bf16x8*)&hw[slot];
    bf16x8 rA1=*(const bf16x8*)&hw[512+slot];
    float y[4][4];
    #pragma unroll
    for(int ot=0;ot<4;ot++){
      f32x4 rc=zero;
      rc=MFMA16(rA0,*(const bf16x8*)&wr2s[ot*512+slot],rc);
      rc=MFMA16(rA1,*(const bf16x8*)&wr2s[2048+ot*512+slot],rc);
      #pragma unroll
      for(int j=0;j<4;j++){
        float zd=zrow[(size_t)(lg*4+j)*DD + ot*16+lr];
        y[ot][j]=zd + rc[j] + br2v[ot];
      }
    }
    #pragma unroll
    for(int j=0;j<4;j++){
      float s=y[0][j]+y[1][j]+y[2][j]+y[3][j];
      s+=__shfl_xor(s,1,64); s+=__shfl_xor(s,2,64); s+=__shfl_xor(s,4,64); s+=__shfl_xor(s,8,64);
      float mean=s*(1.f/64.f);
      float t0=y[0][j]-mean, t1=y[1][j]-mean, t2=y[2][j]-mean, t3=y[3][j]-mean;
      float s2=t0*t0+t1*t1+t2*t2+t3*t3;
      s2+=__shfl_xor(s2,1,64); s2+=__shfl_xor(s2,2,64); s2+=__shfl_xor(s2,4,64); s2+=__shfl_xor(s2,8,64);
      float inv=rsqrtf(s2*(1.f/64.f)+LN_EPS);
      zrow[(size_t)(lg*4+j)*DD +  0+lr]=t0*inv*gv[0]+bv[0];
      zrow[(size_t)(lg*4+j)*DD + 16+lr]=t1*inv*gv[1]+bv[1];
      zrow[(size_t)(lg*4+j)*DD + 32+lr]=t2*inv*gv[2]+bv[2];
      zrow[(size_t)(lg*4+j)*DD + 48+lr]=t3*inv*gv[3]+bv[3];
    }
  }
}

// ---------------- gate2 v3: bf16 MFMA 16x16x32 (unchanged) ----------------
__global__ __launch_bounds__(512) void k_gate2(
    const float* __restrict__ tem, const float* __restrict__ hyp,
    float* __restrict__ x, float* __restrict__ out,
    const float* __restrict__ Wg1,const float* __restrict__ bg1,
    const float* __restrict__ Wg2,const float* __restrict__ bg2,
    const float* __restrict__ Wr1,const float* __restrict__ br1,
    const float* __restrict__ Wr2,const float* __restrict__ br2,
    const float* __restrict__ lng,const float* __restrict__ lnb){
  __shared__ __align__(16) short g1s[4*4*512];
  __shared__ __align__(16) short r1s[4*4*512];
  __shared__ __align__(16) short g2s[2*4*512];
  __shared__ __align__(16) short r2s[2*4*512];
  __shared__ __align__(16) short hls[8][2][1024];
  int tid=threadIdx.x;
  for(int t=tid;t<8192;t+=512){
    int j=t&7,kg=(t>>3)&3,c=(t>>5)&15,ot=(t>>9)&3,kb=t>>11;
    int k=kb*32+kg*4+(j&3)+((j>>2)<<4), o=ot*16+c;
    g1s[t]=f2bf(Wg1[k*64+o]);
    r1s[t]=f2bf(Wr1[k*64+o]);
  }
  for(int t=tid;t<4096;t+=512){
    int j=t&7,kg=(t>>3)&3,c=(t>>5)&15,ot=(t>>9)&3,kb=t>>11;
    int k=kb*32+kg*4+(j&3)+((j>>2)<<4), o=ot*16+c;
    g2s[t]=f2bf(Wg2[k*64+o]);
    r2s[t]=f2bf(Wr2[k*64+o]);
  }
  __syncthreads();
  int wave=tid>>6, l=tid&63;
  int lr=l&15, lg=l>>4;
  float bg1v[4],br1v[4],bg2v[4],br2v[4],gv[4],bv[4];
  #pragma unroll
  for(int ot=0;ot<4;ot++){
    bg1v[ot]=bg1[ot*16+lr]; br1v[ot]=br1[ot*16+lr];
    bg2v[ot]=bg2[ot*16+lr]; br2v[ot]=br2[ot*16+lr];
    gv[ot]=lng[ot*16+lr];   bv[ot]=lnb[ot*16+lr];
  }
  short* hG=&hls[wave][0][0];
  short* hR=&hls[wave][1][0];
  int slot=(lr*4+lg)*8;
  const f32x4 zero={0.f,0.f,0.f,0.f};
  for(int tile=blockIdx.x*8+wave; tile<NND/16; tile+=gridDim.x*8){
    int n0=tile*16;
    const float* xrow=x+(size_t)n0*DD;
    bf16x8 pA0=loadA(xrow,l,0), pA1=loadA(xrow,l,32);
    f32x4 pg[4],pr[4];
    #pragma unroll
    for(int ot=0;ot<4;ot++){
      f32x4 ag=zero, ar=zero;
      ag=MFMA16(pA0,*(const bf16x8*)&g1s[(2*4+ot)*512+slot],ag);
      ag=MFMA16(pA1,*(const bf16x8*)&g1s[(3*4+ot)*512+slot],ag);
      ar=MFMA16(pA0,*(const bf16x8*)&r1s[(2*4+ot)*512+slot],ar);
      ar=MFMA16(pA1,*(const bf16x8*)&r1s[(3*4+ot)*512+slot],ar);
      pg[ot]=ag; pr[ot]=ar;
    }
    float ya[4][4];
    #pragma unroll
    for(int p=0;p<2;p++){
      const float* cur=(p? hyp : tem)+(size_t)n0*DD;
      bf16x8 cA0=loadA(cur,l,0), cA1=loadA(cur,l,32);
      #pragma unroll
      for(int ot=0;ot<4;ot++){
        f32x4 ag=pg[ot], ar=pr[ot];
        ag=MFMA16(cA0,*(const bf16x8*)&g1s[(0*4+ot)*512+slot],ag);
        ag=MFMA16(cA1,*(const bf16x8*)&g1s[(1*4+ot)*512+slot],ag);
        ar=MFMA16(cA0,*(const bf16x8*)&r1s[(0*4+ot)*512+slot],ar);
        ar=MFMA16(cA1,*(const bf16x8*)&r1s[(1*4+ot)*512+slot],ar);
        int kb2=ot>>1;
        #pragma unroll
        for(int j=0;j<4;j++){
          int addr=kb2*512 + ((lg*4+j)*4 + (lr>>2))*8 + ((ot&1)<<2) + (l&3);
          hG[addr]=f2bf(fmaxf(ag[j]+bg1v[ot],0.f));
          hR[addr]=f2bf(leaky(ar[j]+br1v[ot]));
        }
      }
      bf16x8 hgA0=*(const bf16x8*)&hG[slot],    hgA1=*(const bf16x8*)&hG[512+slot];
      bf16x8 hrA0=*(const bf16x8*)&hR[slot],    hrA1=*(const bf16x8*)&hR[512+slot];
      f32x4 g2a[4], r2a[4];
      #pragma unroll
      for(int ot=0;ot<4;ot++){
        f32x4 ag=zero, ar=zero;
        ag=MFMA16(hgA0,*(const bf16x8*)&g2s[(0*4+ot)*512+slot],ag);
        ag=MFMA16(hgA1,*(const bf16x8*)&g2s[(1*4+ot)*512+slot],ag);
        ar=MFMA16(hrA0,*(const bf16x8*)&r2s[(0*4+ot)*512+slot],ar);
        ar=MFMA16(hrA1,*(const bf16x8*)&r2s[(1*4+ot)*512+slot],ar);
        g2a[ot]=ag; r2a[ot]=ar;
      }
      float y[4][4];
      #pragma unroll
      for(int ot=0;ot<4;ot++){
        #pragma unroll
        for(int j=0;j<4;j++){
          float cd=cur[(size_t)(lg*4+j)*DD + ot*16+lr];
          float gw=1.f/(1.f+expf(-(g2a[ot][j]+bg2v[ot])));
          y[ot][j]=gw*(r2a[ot][j]+br2v[ot])+cd;
        }
      }
      #pragma unroll
      for(int j=0;j<4;j++){
        float s=y[0][j]+y[1][j]+y[2][j]+y[3][j];
        s+=__shfl_xor(s,1,64); s+=__shfl_xor(s,2,64); s+=__shfl_xor(s,4,64); s+=__shfl_xor(s,8,64);
        float mean=s*(1.f/64.f);
        float t0=y[0][j]-mean, t1=y[1][j]-mean, t2=y[2][j]-mean, t3=y[3][j]-mean;
        float s2=t0*t0+t1*t1+t2*t2+t3*t3;
        s2+=__shfl_xor(s2,1,64); s2+=__shfl_xor(s2,2,64); s2+=__shfl_xor(s2,4,64); s2+=__shfl_xor(s2,8,64);
        float inv=rsqrtf(s2*(1.f/64.f)+LN_EPS);
        float yn0=t0*inv*gv[0]+bv[0];
        float yn1=t1*inv*gv[1]+bv[1];
        float yn2=t2*inv*gv[2]+bv[2];
        float yn3=t3*inv*gv[3]+bv[3];
        if(p==0){ ya[0][j]=yn0; ya[1][j]=yn1; ya[2][j]=yn2; ya[3][j]=yn3; }
        else    { ya[0][j]+=yn0; ya[1][j]+=yn1; ya[2][j]+=yn2; ya[3][j]+=yn3; }
      }
    }
    #pragma unroll
    for(int ot=0;ot<4;ot++){
      #pragma unroll
      for(int j=0;j<4;j++){
        size_t idx=(size_t)(n0+lg*4+j)*DD + ot*16+lr;
        x[idx]=ya[ot][j];
        out[idx]+=ya[ot][j];
      }
    }
  }
}

extern "C" void kernel_launch(void* const* d_in, const int* in_sizes, int n_in,
                              void* d_out, int out_size, void* d_ws, size_t ws_size,
                              hipStream_t stream){
  const float* uE  =(const float*)d_in[0];
  const float* iE  =(const float*)d_in[1];
  const float* uH  =(const float*)d_in[2];
  const float* iH  =(const float*)d_in[3];
  const float* uA  =(const float*)d_in[4];
  const float* iA  =(const float*)d_in[5];
  const float* dW1 =(const float*)d_in[6];
  const float* db1 =(const float*)d_in[7];
  const float* dW2 =(const float*)d_in[8];
  const float* db2 =(const float*)d_in[9];
  const float* dWr1=(const float*)d_in[10];
  const float* dbr1=(const float*)d_in[11];
  const float* dWr2=(const float*)d_in[12];
  const float* dbr2=(const float*)d_in[13];
  const float* dwts=(const float*)d_in[14];
  const float* dlng=(const float*)d_in[15];
  const float* dlnb=(const float*)d_in[16];
  const float* gWg1=(const float*)d_in[17];
  const float* gbg1=(const float*)d_in[18];
  const float* gWg2=(const float*)d_in[19];
  const float* gbg2=(const float*)d_in[20];
  const float* gWr1=(const float*)d_in[21];
  const float* gbr1=(const float*)d_in[22];
  const float* gWr2=(const float*)d_in[23];
  const float* gbr2=(const float*)d_in[24];
  const float* glng=(const float*)d_in[25];
  const float* glnb=(const float*)d_in[26];
  const float* avals=(const float*)d_in[27];
  const int*   arows=(const int*)d_in[28];
  const int*   acols=(const int*)d_in[29];
  float* out=(float*)d_out;
  float* ws =(float*)d_ws;

  size_t need = ((size_t)3*NND*DD + NND + 128 + 8192 + 8192 + 8)*sizeof(float);
  if(ws_size < need) return;

  float* x   = ws;
  float* tem = x   + (size_t)NND*DD;
  float* hyp = tem + (size_t)NND*DD;
  float* a   = hyp + (size_t)NND*DD;
  float* hv  = a   + NND;
  float* G   = hv  + 128;
  float* Mb  = G   + 8192;
  float* red = Mb  + 8192;

  // CSR scratch aliased into the hyp buffer (dead until k_hyp2 writes it each layer)
  int*   ecol  = (int*)hyp;
  float* eval  = hyp + EDG;
  int*   rowptr= (int*)(hyp + 2*(size_t)EDG);
  int*   wcur  = rowptr + (NND+1);
  int*   bsum  = wcur + NND;

  hipMemsetAsync(red, 0, 8*sizeof(float), stream);
  k_init<<<2048,256,0,stream>>>(uE,iE,x,out);
  k_hv<<<1,128,0,stream>>>(uH,iH,uA,iA,hv);
  k_att<<<256,256,0,stream>>>(uE,hv,a,USERN);
  k_att<<<256,256,0,stream>>>(iE,hv+64,a+USERN,ITEMN);
  k_redmax<<<256,256,0,stream>>>(a,USERN,(unsigned*)red);
  k_redmax<<<256,256,0,stream>>>(a+USERN,ITEMN,(unsigned*)red+2);
  k_sumexp<<<256,256,0,stream>>>(a,USERN,(const unsigned*)red,red+1);
  k_sumexp<<<256,256,0,stream>>>(a+USERN,ITEMN,(const unsigned*)red+2,red+3);
  k_scale_a<<<256,256,0,stream>>>(a,USERN,(const unsigned*)red,red+1);
  k_scale_a<<<256,256,0,stream>>>(a+USERN,ITEMN,(const unsigned*)red+2,red+3);

  for(int i=0;i<2;i++){
    // build CSR (hyp region is free until k_hyp2 below)
    hipMemsetAsync(rowptr,0,(NND+1)*sizeof(int),stream);
    k_hist<<<2048,256,0,stream>>>(arows,rowptr);
    k_scanA<<<SNB,256,0,stream>>>(rowptr,bsum);
    k_scanB<<<1,512,0,stream>>>(bsum);
    k_scanC<<<2048,256,0,stream>>>(rowptr,bsum,wcur);
    k_scatter<<<2048,256,0,stream>>>(arows,acols,avals,wcur,ecol,eval);
    k_spmm_csr<<<4096,512,0,stream>>>(rowptr,ecol,eval,x,tem);

    hipMemsetAsync(G,0,8192*sizeof(float),stream);
    k_gacc<<<256,256,0,stream>>>(uE,a,x,G,USERN);
    k_gacc<<<256,256,0,stream>>>(iE,a+USERN,x+(size_t)USERN*DD,G+4096,ITEMN);
    k_tm<<<2,256,0,stream>>>(uH,iH,G,Mb);
    k_hyp2<<<256,256,0,stream>>>(uE,a,Mb,hyp,USERN);
    k_hyp2<<<256,256,0,stream>>>(iE,a+USERN,Mb+4096,hyp+(size_t)USERN*DD,ITEMN);
    for(int j=0;j<2;j++){
      float* zb=(j==0)? tem : hyp;
      int ij=i*2+j;
      k_dis<<<512,512,0,stream>>>(zb,
        dW1+(size_t)ij*4*64*64, db1+(size_t)ij*4*64,
        dW2+(size_t)ij*4*64*16, db2+(size_t)ij*4*16,
        dWr1+(size_t)ij*16*64,  dbr1+(size_t)ij*64,
        dWr2+(size_t)ij*64*64,  dbr2+(size_t)ij*64,
        dwts+(size_t)ij*4, dlng+(size_t)ij*64, dlnb+(size_t)ij*64);
    }
    k_gate2<<<512,512,0,stream>>>(tem,hyp,x,out,
      gWg1+(size_t)i*128*64, gbg1+(size_t)i*64,
      gWg2+(size_t)i*64*64,  gbg2+(size_t)i*64,
      gWr1+(size_t)i*128*64, gbr1+(size_t)i*64,
      gWr2+(size_t)i*64*64,  gbr2+(size_t)i*64,
      glng+(size_t)i*64, glnb+(size_t)i*64);
  }
}

// Round 7
// 2233.157 us; speedup vs baseline: 8.4864x; 1.1878x over previous
//
#include <hip/hip_runtime.h>
#include <math.h>

#define USERN 100000
#define ITEMN 200000
#define NND   300000
#define DD    64
#define HH    128
#define FF    16
#define EDG   3000000
#define LEAKY_A 0.5f
#define LN_EPS  1e-5f
#define SCHUNK 1024
#define SNB ((NND+SCHUNK-1)/SCHUNK)

typedef __attribute__((ext_vector_type(8))) short bf16x8;
typedef __attribute__((ext_vector_type(4))) float f32x4;
#define MFMA16(a,b,c) __builtin_amdgcn_mfma_f32_16x16x32_bf16(a,b,c,0,0,0)

__device__ __forceinline__ float leaky(float x){ return x>0.f ? x : LEAKY_A*x; }
__device__ __forceinline__ unsigned fenc(float f){ unsigned u=__float_as_uint(f); return (u&0x80000000u)? ~u : (u|0x80000000u); }
__device__ __forceinline__ float fdec(unsigned u){ return (u&0x80000000u)? __uint_as_float(u&0x7fffffffu) : __uint_as_float(~u); }
__device__ __forceinline__ short f2bf(float f){
  unsigned u=__float_as_uint(f);
  unsigned r=u + 0x7fffu + ((u>>16)&1u);
  return (short)(r>>16);
}
__device__ __forceinline__ bf16x8 loadA(const float* __restrict__ base, int l, int dbase){
  const float* p = base + (size_t)(l&15)*DD + dbase + ((l>>4)<<2);
  float4 a=*(const float4*)p;
  float4 b=*(const float4*)(p+16);
  bf16x8 r;
  r[0]=f2bf(a.x); r[1]=f2bf(a.y); r[2]=f2bf(a.z); r[3]=f2bf(a.w);
  r[4]=f2bf(b.x); r[5]=f2bf(b.y); r[6]=f2bf(b.z); r[7]=f2bf(b.w);
  return r;
}

// ---------------- init: x = concat(uE, iE); out = x ----------------
__global__ __launch_bounds__(256) void k_init(const float* __restrict__ uE, const float* __restrict__ iE,
                        float* __restrict__ x, float* __restrict__ out){
  int tot=NND*DD;
  for(int idx=blockIdx.x*256+threadIdx.x; idx<tot; idx+=gridDim.x*256){
    int n=idx>>6;
    float v=(n<USERN)? uE[idx] : iE[idx-USERN*DD];
    x[idx]=v; out[idx]=v;
  }
}

// ---------------- hv = H @ attn (hv[0:64]=u, hv[64:128]=i) ----------------
__global__ __launch_bounds__(128) void k_hv(const float* __restrict__ uH,const float* __restrict__ iH,
      const float* __restrict__ uA,const float* __restrict__ iA,float* __restrict__ hv){
  int t=threadIdx.x;
  const float* H=(t<64)? uH:iH;
  const float* A=(t<64)? uA:iA;
  int d=t&63;
  float s=0.f;
  for(int h=0;h<HH;h++) s=fmaf(H[d*HH+h],A[h],s);
  hv[t]=s;
}

// ---------------- a[n] = E[n,:] . hv ----------------
__global__ __launch_bounds__(256) void k_att(const float* __restrict__ E, const float* __restrict__ hvp,
      float* __restrict__ a, int U){
  __shared__ float hs[64];
  int tid=threadIdx.x;
  if(tid<64) hs[tid]=hvp[tid];
  __syncthreads();
  int wave=tid>>6, lane=tid&63;
  for(int g=blockIdx.x*4+wave; g<U/4; g+=gridDim.x*4){
    int n0=g*4;
    #pragma unroll
    for(int m=0;m<4;m++){
      float p=E[(size_t)(n0+m)*DD+lane]*hs[lane];
      #pragma unroll
      for(int off=32;off;off>>=1) p+=__shfl_xor(p,off,64);
      if(lane==0) a[n0+m]=p;
    }
  }
}

// ---------------- softmax reductions over node axis ----------------
__global__ __launch_bounds__(256) void k_redmax(const float* __restrict__ a, int n, unsigned* slot){
  float v=-3.0e38f;
  for(int i=blockIdx.x*256+threadIdx.x;i<n;i+=gridDim.x*256) v=fmaxf(v,a[i]);
  #pragma unroll
  for(int off=32;off;off>>=1) v=fmaxf(v,__shfl_xor(v,off,64));
  if((threadIdx.x&63)==0) atomicMax(slot, fenc(v));
}

__global__ __launch_bounds__(256) void k_sumexp(const float* __restrict__ a, int n,
      const unsigned* __restrict__ mslot, float* ssum){
  float mx=fdec(*mslot);
  float s=0.f;
  for(int i=blockIdx.x*256+threadIdx.x;i<n;i+=gridDim.x*256) s+=expf(a[i]-mx);
  #pragma unroll
  for(int off=32;off;off>>=1) s+=__shfl_xor(s,off,64);
  if((threadIdx.x&63)==0) atomicAdd(ssum, s);
}

__global__ __launch_bounds__(256) void k_scale_a(float* __restrict__ a,int n,
      const unsigned* __restrict__ mslot,const float* __restrict__ ssum){
  float mx=fdec(*mslot); float inv=1.f/(*ssum);
  for(int i=blockIdx.x*256+threadIdx.x;i<n;i+=gridDim.x*256) a[i]=expf(a[i]-mx)*inv;
}

// ---------------- CSR build: histogram -> scan -> scatter ----------------
__global__ __launch_bounds__(256) void k_hist(const int* __restrict__ rows, int* __restrict__ cnt){
  for(int e=blockIdx.x*256+threadIdx.x; e<EDG; e+=gridDim.x*256)
    atomicAdd(&cnt[rows[e]],1);
}

__global__ __launch_bounds__(256) void k_scanA(int* __restrict__ cnt, int* __restrict__ bsum){
  __shared__ int part[256];
  int b=blockIdx.x, t=threadIdx.x;
  int base=b*SCHUNK;
  int v[4]; int s=0;
  #pragma unroll
  for(int k2=0;k2<4;k2++){
    int idx=base+t*4+k2;
    int val=(idx<NND)? cnt[idx]:0;
    v[k2]=s; s+=val;
  }
  part[t]=s;
  __syncthreads();
  for(int off=1;off<256;off<<=1){
    int y=(t>=off)? part[t-off]:0;
    __syncthreads();
    part[t]+=y;
    __syncthreads();
  }
  int excl=(t==0)?0:part[t-1];
  #pragma unroll
  for(int k2=0;k2<4;k2++){
    int idx=base+t*4+k2;
    if(idx<NND) cnt[idx]=excl+v[k2];
  }
  if(t==255) bsum[b]=part[255];
}

__global__ __launch_bounds__(512) void k_scanB(int* __restrict__ bsum){
  __shared__ int part[512];
  int t=threadIdx.x;
  part[t]=(t<SNB)? bsum[t]:0;
  __syncthreads();
  for(int off=1;off<512;off<<=1){
    int y=(t>=off)? part[t-off]:0;
    __syncthreads();
    part[t]+=y;
    __syncthreads();
  }
  if(t<SNB) bsum[t]=(t==0)?0:part[t-1];
}

__global__ __launch_bounds__(256) void k_scanC(int* __restrict__ rowptr, const int* __restrict__ bsum,
      int* __restrict__ wcur){
  for(int i=blockIdx.x*256+threadIdx.x; i<NND; i+=gridDim.x*256){
    int v=rowptr[i]+bsum[i>>10];
    rowptr[i]=v; wcur[i]=v;
  }
  if(blockIdx.x==0 && threadIdx.x==0) rowptr[NND]=EDG;
}

__global__ __launch_bounds__(256) void k_scatter(const int* __restrict__ rows,const int* __restrict__ cols,
      const float* __restrict__ vals, int* __restrict__ wcur,
      int* __restrict__ ecol, float* __restrict__ eval){
  for(int e=blockIdx.x*256+threadIdx.x; e<EDG; e+=gridDim.x*256){
    int r=rows[e];
    int pos=atomicAdd(&wcur[r],1);
    ecol[pos]=cols[e];
    eval[pos]=vals[e];
  }
}

// ---------------- CSR SpMM: wave per row, no atomics ----------------
__global__ __launch_bounds__(512) void k_spmm_csr(const int* __restrict__ rowptr,
      const int* __restrict__ ecol, const float* __restrict__ eval,
      const float* __restrict__ x, float* __restrict__ tem){
  int wave=threadIdx.x>>6, lane=threadIdx.x&63;
  for(int r=blockIdx.x*8+wave; r<NND; r+=gridDim.x*8){
    int st=rowptr[r], en=rowptr[r+1];
    float acc=0.f;
    int p=st;
    for(; p+1<en; p+=2){
      int c0=ecol[p], c1=ecol[p+1];
      float v0=eval[p], v1=eval[p+1];
      float x0=x[(size_t)c0*DD+lane];
      float x1=x[(size_t)c1*DD+lane];
      acc=fmaf(v0,x0,acc);
      acc=fmaf(v1,x1,acc);
    }
    if(p<en) acc=fmaf(eval[p], x[(size_t)ecol[p]*DD+lane], acc);
    tem[(size_t)r*DD+lane]=acc;
  }
}

// ---------------- G[d1,d2] += sum_n s[n]*E[n,d1]*x[n,d2] ----------------
__global__ __launch_bounds__(256) void k_gacc(const float* __restrict__ E,const float* __restrict__ sca,
      const float* __restrict__ x,float* __restrict__ G,int U){
  __shared__ __align__(16) float es[4][256];
  int tid=threadIdx.x, wave=tid>>6, lane=tid&63;
  float acc[64];
  #pragma unroll
  for(int j=0;j<64;j++) acc[j]=0.f;
  float* esw=es[wave];
  for(int g=blockIdx.x*4+wave; g<U/4; g+=gridDim.x*4){
    int n0=g*4;
    float xv[4];
    #pragma unroll
    for(int m=0;m<4;m++){
      float sc=sca[n0+m];
      esw[m*64+lane]=E[(size_t)(n0+m)*DD+lane]*sc;
      xv[m]=x[(size_t)(n0+m)*DD+lane];
    }
    #pragma unroll
    for(int d4=0;d4<16;d4++){
      float4 eb[4];
      #pragma unroll
      for(int m=0;m<4;m++) eb[m]=((const float4*)(esw+m*64))[d4];
      #pragma unroll
      for(int c=0;c<4;c++){
        #pragma unroll
        for(int m=0;m<4;m++) acc[d4*4+c]=fmaf(((const float*)&eb[m])[c],xv[m],acc[d4*4+c]);
      }
    }
  }
  #pragma unroll
  for(int j=0;j<64;j++) atomicAdd(&G[j*64+lane],acc[j]);
}

// ---------------- M = H @ (H^T @ G)  (blockIdx 0=user, 1=item) ----------------
__global__ __launch_bounds__(256) void k_tm(const float* __restrict__ uH,const float* __restrict__ iH,
      const float* __restrict__ G,float* __restrict__ Mo){
  __shared__ __align__(16) float Hs[64*HH];
  __shared__ __align__(16) float Gs[64*64];
  __shared__ __align__(16) float Ts[HH*64];
  const float* H = blockIdx.x ? iH : uH;
  const float* Gp = G + blockIdx.x*4096;
  float* Mp = Mo + blockIdx.x*4096;
  int tid=threadIdx.x;
  for(int k=tid;k<64*HH;k+=256) Hs[k]=H[k];
  for(int k=tid;k<4096;k+=256) Gs[k]=Gp[k];
  __syncthreads();
  int lane=tid&63, wq=tid>>6;
  float tac[32];
  #pragma unroll
  for(int k=0;k<32;k++) tac[k]=0.f;
  for(int d1=0;d1<64;d1++){
    float gv=Gs[d1*64+lane];
    const float4* hrow=(const float4*)(Hs+d1*HH+wq*32);
    #pragma unroll
    for(int k4=0;k4<8;k4++){
      float4 hb=hrow[k4];
      tac[k4*4+0]=fmaf(hb.x,gv,tac[k4*4+0]);
      tac[k4*4+1]=fmaf(hb.y,gv,tac[k4*4+1]);
      tac[k4*4+2]=fmaf(hb.z,gv,tac[k4*4+2]);
      tac[k4*4+3]=fmaf(hb.w,gv,tac[k4*4+3]);
    }
  }
  #pragma unroll
  for(int k=0;k<32;k++) Ts[(wq*32+k)*64+lane]=tac[k];
  __syncthreads();
  float mac[16];
  #pragma unroll
  for(int k=0;k<16;k++) mac[k]=0.f;
  for(int h=0;h<HH;h++){
    float tv=Ts[h*64+lane];
    #pragma unroll
    for(int k=0;k<16;k++) mac[k]=fmaf(Hs[(wq*16+k)*HH+h],tv,mac[k]);
  }
  #pragma unroll
  for(int k=0;k<16;k++) Mp[(wq*16+k)*64+lane]=mac[k];
}

// ---------------- hyp[n,:] = s[n] * E[n,:] @ M ----------------
__global__ __launch_bounds__(256) void k_hyp2(const float* __restrict__ E,const float* __restrict__ sca,
      const float* __restrict__ Mp,float* __restrict__ hyp,int U){
  __shared__ __align__(16) float es[4][256];
  int tid=threadIdx.x, wave=tid>>6, lane=tid&63;
  float mcol[64];
  #pragma unroll
  for(int j=0;j<64;j++) mcol[j]=Mp[j*64+lane];
  float* esw=es[wave];
  for(int g=blockIdx.x*4+wave; g<U/4; g+=gridDim.x*4){
    int n0=g*4;
    #pragma unroll
    for(int m=0;m<4;m++){
      float sc=sca[n0+m];
      esw[m*64+lane]=E[(size_t)(n0+m)*DD+lane]*sc;
    }
    float acc[4]={0,0,0,0};
    #pragma unroll
    for(int d4=0;d4<16;d4++){
      float4 eb[4];
      #pragma unroll
      for(int m=0;m<4;m++) eb[m]=((const float4*)(esw+m*64))[d4];
      #pragma unroll
      for(int c=0;c<4;c++){
        float mv=mcol[d4*4+c];
        #pragma unroll
        for(int m=0;m<4;m++) acc[m]=fmaf(((const float*)&eb[m])[c],mv,acc[m]);
      }
    }
    #pragma unroll
    for(int m=0;m<4;m++) hyp[(size_t)(n0+m)*DD+lane]=acc[m];
  }
}

// ---------------- dis v3: bf16 MFMA 16x16x32 (unchanged) ----------------
__global__ __launch_bounds__(512) void k_dis(
    float* __restrict__ z,
    const float* __restrict__ W1,const float* __restrict__ b1,
    const float* __restrict__ W2,const float* __restrict__ b2,
    const float* __restrict__ Wr1,const float* __restrict__ br1,
    const float* __restrict__ Wr2,const float* __restrict__ br2,
    const float* __restrict__ wsoft,const float* __restrict__ lng,const float* __restrict__ lnb){
  __shared__ __align__(16) short w1s[16384];
  __shared__ __align__(16) short w2s[4096];
  __shared__ __align__(16) short wr1s[2048];
  __shared__ __align__(16) short wr2s[4096];
  __shared__ __align__(16) short hst[8][1024];
  __shared__ __align__(16) short cst[8][512];
  __shared__ float swsh[4];
  int tid=threadIdx.x;
  for(int t=tid;t<16384;t+=512){
    int j=t&7,kg=(t>>3)&3,c=(t>>5)&15,ot=(t>>9)&3,kb=(t>>11)&1,kk=t>>12;
    int k=kb*32+kg*4+(j&3)+((j>>2)<<4), o=ot*16+c;
    w1s[t]=f2bf(W1[(size_t)(kk*64+k)*64+o]);
  }
  for(int t=tid;t<4096;t+=512){
    int j=t&7,kg=(t>>3)&3,c=(t>>5)&15,kb=(t>>9)&1,kk=t>>10;
    int k=kb*32+kg*4+(j&3)+((j>>2)<<4);
    w2s[t]=f2bf(W2[(size_t)(kk*64+k)*16+c]);
  }
  for(int t=tid;t<2048;t+=512){
    int j=t&7,kg=(t>>3)&3,c=(t>>5)&15,ot=t>>9;
    int o=ot*16+c;
    short v=0;
    if(j<4){ int k=kg*4+j; v=f2bf(Wr1[k*64+o]); }
    wr1s[t]=v;
  }
  for(int t=tid;t<4096;t+=512){
    int j=t&7,kg=(t>>3)&3,c=(t>>5)&15,ot=(t>>9)&3,kb=t>>11;
    int k=kb*32+kg*4+(j&3)+((j>>2)<<4), o=ot*16+c;
    wr2s[t]=f2bf(Wr2[k*64+o]);
  }
  if(tid==0){
    float m0=fmaxf(fmaxf(wsoft[0],wsoft[1]),fmaxf(wsoft[2],wsoft[3]));
    float e0=expf(wsoft[0]-m0),e1=expf(wsoft[1]-m0),e2=expf(wsoft[2]-m0),e3=expf(wsoft[3]-m0);
    float s=e0+e1+e2+e3;
    swsh[0]=e0/s; swsh[1]=e1/s; swsh[2]=e2/s; swsh[3]=e3/s;
  }
  __syncthreads();
  int wave=tid>>6, l=tid&63, lr=l&15, lg=l>>4;
  float sw[4]; sw[0]=swsh[0]; sw[1]=swsh[1]; sw[2]=swsh[2]; sw[3]=swsh[3];
  float b1v[4][4], br1v[4], br2v[4], gv[4], bv[4];
  #pragma unroll
  for(int kk=0;kk<4;kk++)
    #pragma unroll
    for(int ot=0;ot<4;ot++) b1v[kk][ot]=b1[kk*64+ot*16+lr];
  float b2c = sw[0]*b2[lr] + sw[1]*b2[16+lr] + sw[2]*b2[32+lr] + sw[3]*b2[48+lr];
  #pragma unroll
  for(int ot=0;ot<4;ot++){
    br1v[ot]=br1[ot*16+lr]; br2v[ot]=br2[ot*16+lr];
    gv[ot]=lng[ot*16+lr];   bv[ot]=lnb[ot*16+lr];
  }
  short* hw=hst[wave];
  short* cw=cst[wave];
  for(int t=l;t<256;t+=64){
    int r=t>>4, lgp=(t>>2)&3, jj=t&3;
    cw[(r*4+lgp)*8+4+jj]=0;
  }
  int slot=(lr*4+lg)*8;
  const f32x4 zero={0.f,0.f,0.f,0.f};
  for(int tile=blockIdx.x*8+wave; tile<NND/16; tile+=gridDim.x*8){
    int n0=tile*16;
    float* zrow=z+(size_t)n0*DD;
    bf16x8 A0=loadA(zrow,l,0), A1=loadA(zrow,l,32);
    f32x4 cba; cba[0]=b2c; cba[1]=b2c; cba[2]=b2c; cba[3]=b2c;
    #pragma unroll
    for(int kk=0;kk<4;kk++){
      const short* w1k=&w1s[kk*4096];
      #pragma unroll
      for(int ot=0;ot<4;ot++){
        f32x4 ha=zero;
        ha=MFMA16(A0,*(const bf16x8*)&w1k[ot*512+slot],ha);
        ha=MFMA16(A1,*(const bf16x8*)&w1k[2048+ot*512+slot],ha);
        int kb2=ot>>1;
        #pragma unroll
        for(int j=0;j<4;j++){
          int addr=kb2*512 + ((lg*4+j)*4 + (lr>>2))*8 + ((ot&1)<<2) + (l&3);
          hw[addr]=f2bf(leaky(ha[j]+b1v[kk][ot]));
        }
      }
      bf16x8 hA0=*(const bf16x8*)&hw[slot];
      bf16x8 hA1=*(const bf16x8*)&hw[512+slot];
      f32x4 fa=zero;
      fa=MFMA16(hA0,*(const bf16x8*)&w2s[kk*1024+slot],fa);
      fa=MFMA16(hA1,*(const bf16x8*)&w2s[kk*1024+512+slot],fa);
      float swk=sw[kk];
      #pragma unroll
      for(int j=0;j<4;j++) cba[j]=fmaf(swk,fa[j],cba[j]);
    }
    #pragma unroll
    for(int j=0;j<4;j++)
      cw[((lg*4+j)*4 + (lr>>2))*8 + (lr&3)] = f2bf(cba[j]);
    bf16x8 cA=*(const bf16x8*)&cw[slot];
    #pragma unroll
    for(int ot=0;ot<4;ot++){
      f32x4 ra=MFMA16(cA,*(const bf16x8*)&wr1s[ot*512+slot],zero);
      int kb2=ot>>1;
      #pragma unroll
      for(int j=0;j<4;j++){
        int addr=kb2*512 + ((lg*4+j)*4 + (lr>>2))*8 + ((ot&1)<<2) + (l&3);
        hw[addr]=f2bf(leaky(ra[j]+br1v[ot]));
      }
    }
    bf16x8 rA0=*(const bf16x8*)&hw[slot];
    bf16x8 rA1=*(const bf16x8*)&hw[512+slot];
    float y[4][4];
    #pragma unroll
    for(int ot=0;ot<4;ot++){
      f32x4 rc=zero;
      rc=MFMA16(rA0,*(const bf16x8*)&wr2s[ot*512+slot],rc);
      rc=MFMA16(rA1,*(const bf16x8*)&wr2s[2048+ot*512+slot],rc);
      #pragma unroll
      for(int j=0;j<4;j++){
        float zd=zrow[(size_t)(lg*4+j)*DD + ot*16+lr];
        y[ot][j]=zd + rc[j] + br2v[ot];
      }
    }
    #pragma unroll
    for(int j=0;j<4;j++){
      float s=y[0][j]+y[1][j]+y[2][j]+y[3][j];
      s+=__shfl_xor(s,1,64); s+=__shfl_xor(s,2,64); s+=__shfl_xor(s,4,64); s+=__shfl_xor(s,8,64);
      float mean=s*(1.f/64.f);
      float t0=y[0][j]-mean, t1=y[1][j]-mean, t2=y[2][j]-mean, t3=y[3][j]-mean;
      float s2=t0*t0+t1*t1+t2*t2+t3*t3;
      s2+=__shfl_xor(s2,1,64); s2+=__shfl_xor(s2,2,64); s2+=__shfl_xor(s2,4,64); s2+=__shfl_xor(s2,8,64);
      float inv=rsqrtf(s2*(1.f/64.f)+LN_EPS);
      zrow[(size_t)(lg*4+j)*DD +  0+lr]=t0*inv*gv[0]+bv[0];
      zrow[(size_t)(lg*4+j)*DD + 16+lr]=t1*inv*gv[1]+bv[1];
      zrow[(size_t)(lg*4+j)*DD + 32+lr]=t2*inv*gv[2]+bv[2];
      zrow[(size_t)(lg*4+j)*DD + 48+lr]=t3*inv*gv[3]+bv[3];
    }
  }
}

// ---------------- gate2 v4: bf16 MFMA, single reused h-buffer (64KB LDS -> 2 blocks/CU) ----------------
__global__ __launch_bounds__(512) void k_gate2(
    const float* __restrict__ tem, const float* __restrict__ hyp,
    float* __restrict__ x, float* __restrict__ out,
    const float* __restrict__ Wg1,const float* __restrict__ bg1,
    const float* __restrict__ Wg2,const float* __restrict__ bg2,
    const float* __restrict__ Wr1,const float* __restrict__ br1,
    const float* __restrict__ Wr2,const float* __restrict__ br2,
    const float* __restrict__ lng,const float* __restrict__ lnb){
  __shared__ __align__(16) short g1s[4*4*512];
  __shared__ __align__(16) short r1s[4*4*512];
  __shared__ __align__(16) short g2s[2*4*512];
  __shared__ __align__(16) short r2s[2*4*512];
  __shared__ __align__(16) short hls[8][1024];   // single reused buffer (G then R)
  int tid=threadIdx.x;
  for(int t=tid;t<8192;t+=512){
    int j=t&7,kg=(t>>3)&3,c=(t>>5)&15,ot=(t>>9)&3,kb=t>>11;
    int k=kb*32+kg*4+(j&3)+((j>>2)<<4), o=ot*16+c;
    g1s[t]=f2bf(Wg1[k*64+o]);
    r1s[t]=f2bf(Wr1[k*64+o]);
  }
  for(int t=tid;t<4096;t+=512){
    int j=t&7,kg=(t>>3)&3,c=(t>>5)&15,ot=(t>>9)&3,kb=t>>11;
    int k=kb*32+kg*4+(j&3)+((j>>2)<<4), o=ot*16+c;
    g2s[t]=f2bf(Wg2[k*64+o]);
    r2s[t]=f2bf(Wr2[k*64+o]);
  }
  __syncthreads();
  int wave=tid>>6, l=tid&63;
  int lr=l&15, lg=l>>4;
  float bg1v[4],br1v[4],bg2v[4],br2v[4],gv[4],bv[4];
  #pragma unroll
  for(int ot=0;ot<4;ot++){
    bg1v[ot]=bg1[ot*16+lr]; br1v[ot]=br1[ot*16+lr];
    bg2v[ot]=bg2[ot*16+lr]; br2v[ot]=br2[ot*16+lr];
    gv[ot]=lng[ot*16+lr];   bv[ot]=lnb[ot*16+lr];
  }
  short* hw=hls[wave];
  int slot=(lr*4+lg)*8;
  const f32x4 zero={0.f,0.f,0.f,0.f};
  for(int tile=blockIdx.x*8+wave; tile<NND/16; tile+=gridDim.x*8){
    int n0=tile*16;
    const float* xrow=x+(size_t)n0*DD;
    bf16x8 pA0=loadA(xrow,l,0), pA1=loadA(xrow,l,32);
    f32x4 pg[4],pr[4];
    #pragma unroll
    for(int ot=0;ot<4;ot++){
      f32x4 ag=zero, ar=zero;
      ag=MFMA16(pA0,*(const bf16x8*)&g1s[(2*4+ot)*512+slot],ag);
      ag=MFMA16(pA1,*(const bf16x8*)&g1s[(3*4+ot)*512+slot],ag);
      ar=MFMA16(pA0,*(const bf16x8*)&r1s[(2*4+ot)*512+slot],ar);
      ar=MFMA16(pA1,*(const bf16x8*)&r1s[(3*4+ot)*512+slot],ar);
      pg[ot]=ag; pr[ot]=ar;
    }
    float ya[4][4];
    #pragma unroll
    for(int p=0;p<2;p++){
      const float* cur=(p? hyp : tem)+(size_t)n0*DD;
      bf16x8 cA0=loadA(cur,l,0), cA1=loadA(cur,l,32);
      f32x4 ag[4], ar[4];
      #pragma unroll
      for(int ot=0;ot<4;ot++){
        f32x4 g=pg[ot], r=pr[ot];
        g=MFMA16(cA0,*(const bf16x8*)&g1s[(0*4+ot)*512+slot],g);
        g=MFMA16(cA1,*(const bf16x8*)&g1s[(1*4+ot)*512+slot],g);
        r=MFMA16(cA0,*(const bf16x8*)&r1s[(0*4+ot)*512+slot],r);
        r=MFMA16(cA1,*(const bf16x8*)&r1s[(1*4+ot)*512+slot],r);
        ag[ot]=g; ar[ot]=r;
      }
      // G path through the shared h-buffer
      #pragma unroll
      for(int ot=0;ot<4;ot++){
        int kb2=ot>>1;
        #pragma unroll
        for(int j=0;j<4;j++){
          int addr=kb2*512 + ((lg*4+j)*4 + (lr>>2))*8 + ((ot&1)<<2) + (l&3);
          hw[addr]=f2bf(fmaxf(ag[ot][j]+bg1v[ot],0.f));
        }
      }
      bf16x8 hgA0=*(const bf16x8*)&hw[slot], hgA1=*(const bf16x8*)&hw[512+slot];
      f32x4 g2a[4];
      #pragma unroll
      for(int ot=0;ot<4;ot++){
        f32x4 g=zero;
        g=MFMA16(hgA0,*(const bf16x8*)&g2s[(0*4+ot)*512+slot],g);
        g=MFMA16(hgA1,*(const bf16x8*)&g2s[(1*4+ot)*512+slot],g);
        g2a[ot]=g;
      }
      // R path reuses the same buffer (wave-local WAR handled by waitcnts)
      #pragma unroll
      for(int ot=0;ot<4;ot++){
        int kb2=ot>>1;
        #pragma unroll
        for(int j=0;j<4;j++){
          int addr=kb2*512 + ((lg*4+j)*4 + (lr>>2))*8 + ((ot&1)<<2) + (l&3);
          hw[addr]=f2bf(leaky(ar[ot][j]+br1v[ot]));
        }
      }
      bf16x8 hrA0=*(const bf16x8*)&hw[slot], hrA1=*(const bf16x8*)&hw[512+slot];
      f32x4 r2a[4];
      #pragma unroll
      for(int ot=0;ot<4;ot++){
        f32x4 r=zero;
        r=MFMA16(hrA0,*(const bf16x8*)&r2s[(0*4+ot)*512+slot],r);
        r=MFMA16(hrA1,*(const bf16x8*)&r2s[(1*4+ot)*512+slot],r);
        r2a[ot]=r;
      }
      float y[4][4];
      #pragma unroll
      for(int ot=0;ot<4;ot++){
        #pragma unroll
        for(int j=0;j<4;j++){
          float cd=cur[(size_t)(lg*4+j)*DD + ot*16+lr];
          float gw=1.f/(1.f+expf(-(g2a[ot][j]+bg2v[ot])));
          y[ot][j]=gw*(r2a[ot][j]+br2v[ot])+cd;
        }
      }
      #pragma unroll
      for(int j=0;j<4;j++){
        float s=y[0][j]+y[1][j]+y[2][j]+y[3][j];
        s+=__shfl_xor(s,1,64); s+=__shfl_xor(s,2,64); s+=__shfl_xor(s,4,64); s+=__shfl_xor(s,8,64);
        float mean=s*(1.f/64.f);
        float t0=y[0][j]-mean, t1=y[1][j]-mean, t2=y[2][j]-mean, t3=y[3][j]-mean;
        float s2=t0*t0+t1*t1+t2*t2+t3*t3;
        s2+=__shfl_xor(s2,1,64); s2+=__shfl_xor(s2,2,64); s2+=__shfl_xor(s2,4,64); s2+=__shfl_xor(s2,8,64);
        float inv=rsqrtf(s2*(1.f/64.f)+LN_EPS);
        float yn0=t0*inv*gv[0]+bv[0];
        float yn1=t1*inv*gv[1]+bv[1];
        float yn2=t2*inv*gv[2]+bv[2];
        float yn3=t3*inv*gv[3]+bv[3];
        if(p==0){ ya[0][j]=yn0; ya[1][j]=yn1; ya[2][j]=yn2; ya[3][j]=yn3; }
        else    { ya[0][j]+=yn0; ya[1][j]+=yn1; ya[2][j]+=yn2; ya[3][j]+=yn3; }
      }
    }
    #pragma unroll
    for(int ot=0;ot<4;ot++){
      #pragma unroll
      for(int j=0;j<4;j++){
        size_t idx=(size_t)(n0+lg*4+j)*DD + ot*16+lr;
        x[idx]=ya[ot][j];
        out[idx]+=ya[ot][j];
      }
    }
  }
}

extern "C" void kernel_launch(void* const* d_in, const int* in_sizes, int n_in,
                              void* d_out, int out_size, void* d_ws, size_t ws_size,
                              hipStream_t stream){
  const float* uE  =(const float*)d_in[0];
  const float* iE  =(const float*)d_in[1];
  const float* uH  =(const float*)d_in[2];
  const float* iH  =(const float*)d_in[3];
  const float* uA  =(const float*)d_in[4];
  const float* iA  =(const float*)d_in[5];
  const float* dW1 =(const float*)d_in[6];
  const float* db1 =(const float*)d_in[7];
  const float* dW2 =(const float*)d_in[8];
  const float* db2 =(const float*)d_in[9];
  const float* dWr1=(const float*)d_in[10];
  const float* dbr1=(const float*)d_in[11];
  const float* dWr2=(const float*)d_in[12];
  const float* dbr2=(const float*)d_in[13];
  const float* dwts=(const float*)d_in[14];
  const float* dlng=(const float*)d_in[15];
  const float* dlnb=(const float*)d_in[16];
  const float* gWg1=(const float*)d_in[17];
  const float* gbg1=(const float*)d_in[18];
  const float* gWg2=(const float*)d_in[19];
  const float* gbg2=(const float*)d_in[20];
  const float* gWr1=(const float*)d_in[21];
  const float* gbr1=(const float*)d_in[22];
  const float* gWr2=(const float*)d_in[23];
  const float* gbr2=(const float*)d_in[24];
  const float* glng=(const float*)d_in[25];
  const float* glnb=(const float*)d_in[26];
  const float* avals=(const float*)d_in[27];
  const int*   arows=(const int*)d_in[28];
  const int*   acols=(const int*)d_in[29];
  float* out=(float*)d_out;
  float* ws =(float*)d_ws;

  size_t needBase = ((size_t)3*NND*DD + NND + 128 + 8192 + 8192 + 8)*sizeof(float);
  size_t csrFloats = (size_t)2*EDG + (NND+1) + NND + 512;
  size_t needFull = needBase + csrFloats*sizeof(float);
  if(ws_size < needBase) return;
  bool persist = (ws_size >= needFull);

  float* x   = ws;
  float* tem = x   + (size_t)NND*DD;
  float* hyp = tem + (size_t)NND*DD;
  float* a   = hyp + (size_t)NND*DD;
  float* hv  = a   + NND;
  float* G   = hv  + 128;
  float* Mb  = G   + 8192;
  float* red = Mb  + 8192;

  // CSR: persistent region after red if ws allows; else aliased into hyp (rebuilt per layer)
  float* csrbase = persist ? (red + 8) : hyp;
  int*   ecol  = (int*)csrbase;
  float* eval  = csrbase + EDG;
  int*   rowptr= (int*)(csrbase + 2*(size_t)EDG);
  int*   wcur  = rowptr + (NND+1);
  int*   bsum  = wcur + NND;

  hipMemsetAsync(red, 0, 8*sizeof(float), stream);
  k_init<<<2048,256,0,stream>>>(uE,iE,x,out);
  k_hv<<<1,128,0,stream>>>(uH,iH,uA,iA,hv);
  k_att<<<256,256,0,stream>>>(uE,hv,a,USERN);
  k_att<<<256,256,0,stream>>>(iE,hv+64,a+USERN,ITEMN);
  k_redmax<<<256,256,0,stream>>>(a,USERN,(unsigned*)red);
  k_redmax<<<256,256,0,stream>>>(a+USERN,ITEMN,(unsigned*)red+2);
  k_sumexp<<<256,256,0,stream>>>(a,USERN,(const unsigned*)red,red+1);
  k_sumexp<<<256,256,0,stream>>>(a+USERN,ITEMN,(const unsigned*)red+2,red+3);
  k_scale_a<<<256,256,0,stream>>>(a,USERN,(const unsigned*)red,red+1);
  k_scale_a<<<256,256,0,stream>>>(a+USERN,ITEMN,(const unsigned*)red+2,red+3);

  if(persist){
    hipMemsetAsync(rowptr,0,(NND+1)*sizeof(int),stream);
    k_hist<<<2048,256,0,stream>>>(arows,rowptr);
    k_scanA<<<SNB,256,0,stream>>>(rowptr,bsum);
    k_scanB<<<1,512,0,stream>>>(bsum);
    k_scanC<<<2048,256,0,stream>>>(rowptr,bsum,wcur);
    k_scatter<<<2048,256,0,stream>>>(arows,acols,avals,wcur,ecol,eval);
  }

  for(int i=0;i<2;i++){
    if(!persist){
      hipMemsetAsync(rowptr,0,(NND+1)*sizeof(int),stream);
      k_hist<<<2048,256,0,stream>>>(arows,rowptr);
      k_scanA<<<SNB,256,0,stream>>>(rowptr,bsum);
      k_scanB<<<1,512,0,stream>>>(bsum);
      k_scanC<<<2048,256,0,stream>>>(rowptr,bsum,wcur);
      k_scatter<<<2048,256,0,stream>>>(arows,acols,avals,wcur,ecol,eval);
    }
    k_spmm_csr<<<4096,512,0,stream>>>(rowptr,ecol,eval,x,tem);

    hipMemsetAsync(G,0,8192*sizeof(float),stream);
    k_gacc<<<256,256,0,stream>>>(uE,a,x,G,USERN);
    k_gacc<<<256,256,0,stream>>>(iE,a+USERN,x+(size_t)USERN*DD,G+4096,ITEMN);
    k_tm<<<2,256,0,stream>>>(uH,iH,G,Mb);
    k_hyp2<<<256,256,0,stream>>>(uE,a,Mb,hyp,USERN);
    k_hyp2<<<256,256,0,stream>>>(iE,a+USERN,Mb+4096,hyp+(size_t)USERN*DD,ITEMN);
    for(int j=0;j<2;j++){
      float* zb=(j==0)? tem : hyp;
      int ij=i*2+j;
      k_dis<<<512,512,0,stream>>>(zb,
        dW1+(size_t)ij*4*64*64, db1+(size_t)ij*4*64,
        dW2+(size_t)ij*4*64*16, db2+(size_t)ij*4*16,
        dWr1+(size_t)ij*16*64,  dbr1+(size_t)ij*64,
        dWr2+(size_t)ij*64*64,  dbr2+(size_t)ij*64,
        dwts+(size_t)ij*4, dlng+(size_t)ij*64, dlnb+(size_t)ij*64);
    }
    k_gate2<<<512,512,0,stream>>>(tem,hyp,x,out,
      gWg1+(size_t)i*128*64, gbg1+(size_t)i*64,
      gWg2+(size_t)i*64*64,  gbg2+(size_t)i*64,
      gWr1+(size_t)i*128*64, gbr1+(size_t)i*64,
      gWr2+(size_t)i*64*64,  gbr2+(size_t)i*64,
      glng+(size_t)i*64, glnb+(size_t)i*64);
  }
}